// Round 1
// baseline (644.862 us; speedup 1.0000x reference)
//
#include <hip/hip_runtime.h>
#include <stdint.h>

// ---------------------------------------------------------------------------
// GraphSAGE 2-layer: out = SAGE2(relu(SAGE1(x)))
// SAGE(x) = mean_agg(x@W_l.T) + b + x@W_r.T   (project-then-aggregate rewrite)
// ---------------------------------------------------------------------------

#define D_IN  768
#define D_HID 256
#define N1    512   // concat(W1_l, W1_r) output width

typedef __attribute__((ext_vector_type(8))) short short8;
typedef __attribute__((ext_vector_type(4))) float f32x4;

__device__ __forceinline__ void async_copy16(const void* g, void* l) {
  __builtin_amdgcn_global_load_lds(
      (const __attribute__((address_space(1))) unsigned int*)g,
      (__attribute__((address_space(3))) unsigned int*)l,
      16, 0, 0);
}

__device__ __forceinline__ unsigned short f2bf(float f) {
  union { float f; unsigned u; } v; v.f = f;
  unsigned r = v.u + 0x7FFFu + ((v.u >> 16) & 1u);   // RNE
  return (unsigned short)(r >> 16);
}

// --------------------------- index handling --------------------------------

// If edge_index is int64 (LE), odd 32-bit words of the first E qwords are all 0.
__global__ void detect_k(const unsigned int* __restrict__ w,
                         unsigned int* __restrict__ flag, int E) {
  int i = blockIdx.x * 256 + threadIdx.x;
  unsigned v = (i < E) ? w[2 * i + 1] : 0u;
  unsigned long long any = __ballot(v != 0u);
  if ((threadIdx.x & 63) == 0 && any) atomicOr(flag, 1u);
}

__global__ void cvtidx_k(const void* __restrict__ eidx,
                         const unsigned int* __restrict__ flag,
                         int* __restrict__ src32, int* __restrict__ dst32, int E) {
  int i = blockIdx.x * 256 + threadIdx.x;
  if (i >= E) return;
  if (*flag) {  // int32 data
    const int* p = (const int*)eidx;
    src32[i] = p[i];
    dst32[i] = p[E + i];
  } else {      // int64 data
    const long long* p = (const long long*)eidx;
    src32[i] = (int)p[i];
    dst32[i] = (int)p[E + i];
  }
}

__global__ void count_k(const int* __restrict__ dst, int* __restrict__ counts, int E) {
  int i = blockIdx.x * 256 + threadIdx.x;
  if (i < E) atomicAdd(&counts[dst[i]], 1);
}

// Single-block exclusive scan over counts -> offs[0..M], cursor copy.
__global__ void scan_k(const int* __restrict__ counts, int* __restrict__ offs,
                       int* __restrict__ cursor, int M) {
  __shared__ int ts[1024];
  int t = threadIdx.x;
  int seg = (M + 1023) / 1024;
  int lo = t * seg, hi = lo + seg; if (hi > M) hi = M; if (lo > M) lo = M;
  int s = 0;
  for (int i = lo; i < hi; i++) s += counts[i];
  ts[t] = s;
  __syncthreads();
  for (int off = 1; off < 1024; off <<= 1) {
    int v = 0;
    if (t >= off) v = ts[t - off];
    __syncthreads();
    ts[t] += v;
    __syncthreads();
  }
  int run = ts[t] - s;  // exclusive prefix of this segment
  for (int i = lo; i < hi; i++) {
    offs[i] = run; cursor[i] = run;
    run += counts[i];
  }
  if (t == 1023) offs[M] = ts[1023];
}

__global__ void fill_k(const int* __restrict__ src, const int* __restrict__ dst,
                       int* __restrict__ cursor, int* __restrict__ csr, int E) {
  int i = blockIdx.x * 256 + threadIdx.x;
  if (i >= E) return;
  int pos = atomicAdd(&cursor[dst[i]], 1);
  csr[pos] = src[i];
}

// --------------------------- bf16 conversion -------------------------------

// 8 elements per thread; rows >= M are zero padding.
__global__ void cvtx_k(const float* __restrict__ x, unsigned short* __restrict__ xb,
                       int M, int Mp) {
  int idx = blockIdx.x * 256 + threadIdx.x;   // chunk of 8 elements
  int total = Mp * (D_IN / 8);
  if (idx >= total) return;
  int row = idx / (D_IN / 8);
  int cpos = (idx % (D_IN / 8)) * 8;
  short8 o;
  if (row < M) {
    const float* p = x + (size_t)row * D_IN + cpos;
    float4 f0 = *(const float4*)p;
    float4 f1 = *(const float4*)(p + 4);
    o[0] = (short)f2bf(f0.x); o[1] = (short)f2bf(f0.y);
    o[2] = (short)f2bf(f0.z); o[3] = (short)f2bf(f0.w);
    o[4] = (short)f2bf(f1.x); o[5] = (short)f2bf(f1.y);
    o[6] = (short)f2bf(f1.z); o[7] = (short)f2bf(f1.w);
  } else {
    o = (short8)0;
  }
  *(short8*)(xb + (size_t)idx * 8) = o;
}

// wb rows 0..255 = W1_l, 256..511 = W1_r  (each [256,768])
__global__ void cvtw_k(const float* __restrict__ W1l, const float* __restrict__ W1r,
                       unsigned short* __restrict__ wb) {
  int idx = blockIdx.x * 256 + threadIdx.x;   // chunk of 8
  int total = N1 * (D_IN / 8);
  if (idx >= total) return;
  int row = idx / (D_IN / 8);
  int cpos = (idx % (D_IN / 8)) * 8;
  const float* p = (row < D_HID) ? (W1l + (size_t)row * D_IN + cpos)
                                 : (W1r + (size_t)(row - D_HID) * D_IN + cpos);
  float4 f0 = *(const float4*)p;
  float4 f1 = *(const float4*)(p + 4);
  short8 o;
  o[0] = (short)f2bf(f0.x); o[1] = (short)f2bf(f0.y);
  o[2] = (short)f2bf(f0.z); o[3] = (short)f2bf(f0.w);
  o[4] = (short)f2bf(f1.x); o[5] = (short)f2bf(f1.y);
  o[6] = (short)f2bf(f1.z); o[7] = (short)f2bf(f1.w);
  *(short8*)(wb + (size_t)idx * 8) = o;
}

// --------------------------- layer-1 GEMM ----------------------------------
// C[Mp, 512] = xb[Mp, 768] @ wb[512, 768]^T   (bf16 inputs, fp32 out)
// 128x128 tile, BK=32, 4 waves, each wave 64x64 via 4x4 of 16x16x32 MFMA.
__global__ __launch_bounds__(256) void gemm_k(
    const unsigned short* __restrict__ xb,
    const unsigned short* __restrict__ wb,
    float* __restrict__ C, int Mp) {
  __shared__ unsigned short As[128 * 32];
  __shared__ unsigned short Bs[128 * 32];
  const int tid  = threadIdx.x;
  const int lane = tid & 63;
  const int wid  = tid >> 6;
  const int wr = wid >> 1, wc = wid & 1;
  const int m0 = blockIdx.x * 128;
  const int n0 = blockIdx.y * 128;
  const int l15  = lane & 15;
  const int quad = lane >> 4;

  f32x4 acc[4][4];
#pragma unroll
  for (int r = 0; r < 4; r++)
#pragma unroll
    for (int c = 0; c < 4; c++) acc[r][c] = (f32x4)0.0f;

  for (int k0 = 0; k0 < D_IN; k0 += 32) {
    __syncthreads();   // previous iteration's LDS reads done
#pragma unroll
    for (int l = 0; l < 4; ++l) {
      int chunk = l * 256 + tid;            // 0..1023; wave-uniform A/B split
      if (chunk < 512) {
        int row = chunk >> 2, cg = chunk & 3;
        async_copy16(xb + (size_t)(m0 + row) * D_IN + k0 + cg * 8, &As[chunk * 8]);
      } else {
        int cb = chunk - 512;
        int row = cb >> 2, cg = cb & 3;
        async_copy16(wb + (size_t)(n0 + row) * D_IN + k0 + cg * 8, &Bs[cb * 8]);
      }
    }
    __syncthreads();   // staging drained (compiler emits vmcnt(0) before barrier)

    short8 a[4], b[4];
#pragma unroll
    for (int r = 0; r < 4; r++)
      a[r] = *(const short8*)&As[(wr * 64 + r * 16 + l15) * 32 + quad * 8];
#pragma unroll
    for (int c = 0; c < 4; c++)
      b[c] = *(const short8*)&Bs[(wc * 64 + c * 16 + l15) * 32 + quad * 8];
#pragma unroll
    for (int r = 0; r < 4; r++)
#pragma unroll
      for (int c = 0; c < 4; c++)
        acc[r][c] = __builtin_amdgcn_mfma_f32_16x16x32_bf16(a[r], b[c], acc[r][c], 0, 0, 0);
  }

  // epilogue: C/D layout col=lane&15, row=(lane>>4)*4+reg
  const int crow0 = m0 + wr * 64;
  const int ccol0 = n0 + wc * 64;
#pragma unroll
  for (int r = 0; r < 4; r++)
#pragma unroll
    for (int c = 0; c < 4; c++) {
      int col = ccol0 + c * 16 + l15;
#pragma unroll
      for (int reg = 0; reg < 4; reg++) {
        int row = crow0 + r * 16 + quad * 4 + reg;
        C[(size_t)row * N1 + col] = acc[r][c][reg];
      }
    }
}

// --------------------------- layer-1 aggregate + epilogue ------------------
// h[i][c] = relu( mean_{j in N(i)} C[j][c] + b1[c] + C[i][256+c] )
__global__ void agg1_k(const float* __restrict__ C, const int* __restrict__ offs,
                       const int* __restrict__ csr, const float* __restrict__ b1,
                       float* __restrict__ h, int M) {
  int i = blockIdx.x;
  int c = threadIdx.x;   // 256 threads
  int s = offs[i], e = offs[i + 1];
  float acc = 0.0f;
  for (int t = s; t < e; t++) {
    int j = csr[t];
    acc += C[(size_t)j * N1 + c];
  }
  float inv = 1.0f / fmaxf((float)(e - s), 1.0f);
  float v = acc * inv + b1[c] + C[(size_t)i * N1 + D_HID + c];
  h[(size_t)i * D_HID + c] = fmaxf(v, 0.0f);
}

// --------------------------- layer-2 GEMV ----------------------------------
// rs[i] = { h[i]@W2_l[0], h[i]@W2_l[1], h[i]@W2_r[0], h[i]@W2_r[1] }
__global__ void l2_k(const float* __restrict__ h, const float* __restrict__ W2l,
                     const float* __restrict__ W2r, float4* __restrict__ rs, int M) {
  int tid = threadIdx.x;
  int lane = tid & 63;
  int wid = tid >> 6;
  int wave = blockIdx.x * 4 + wid;
  int nw = gridDim.x * 4;
  int c = lane * 4;
  float4 wl0 = *(const float4*)(W2l + c);
  float4 wl1 = *(const float4*)(W2l + D_HID + c);
  float4 wr0 = *(const float4*)(W2r + c);
  float4 wr1 = *(const float4*)(W2r + D_HID + c);
  for (int i = wave; i < M; i += nw) {
    float4 hv = *(const float4*)(h + (size_t)i * D_HID + c);
    float r0 = hv.x * wl0.x + hv.y * wl0.y + hv.z * wl0.z + hv.w * wl0.w;
    float r1 = hv.x * wl1.x + hv.y * wl1.y + hv.z * wl1.z + hv.w * wl1.w;
    float s0 = hv.x * wr0.x + hv.y * wr0.y + hv.z * wr0.z + hv.w * wr0.w;
    float s1 = hv.x * wr1.x + hv.y * wr1.y + hv.z * wr1.z + hv.w * wr1.w;
#pragma unroll
    for (int off = 32; off > 0; off >>= 1) {
      r0 += __shfl_xor(r0, off);
      r1 += __shfl_xor(r1, off);
      s0 += __shfl_xor(s0, off);
      s1 += __shfl_xor(s1, off);
    }
    if (lane == 0) rs[i] = make_float4(r0, r1, s0, s1);
  }
}

// --------------------------- final -----------------------------------------
// out[i][j] = mean_{k in N(i)} rs[k][j] + b2[j] + rs[i][2+j]
__global__ void final_k(const float4* __restrict__ rs, const int* __restrict__ offs,
                        const int* __restrict__ csr, const float* __restrict__ b2,
                        float* __restrict__ out, int M) {
  int i = blockIdx.x * 256 + threadIdx.x;
  if (i >= M) return;
  int s = offs[i], e = offs[i + 1];
  float a0 = 0.0f, a1 = 0.0f;
  for (int t = s; t < e; t++) {
    float4 v = rs[csr[t]];
    a0 += v.x; a1 += v.y;
  }
  float inv = 1.0f / fmaxf((float)(e - s), 1.0f);
  float4 me = rs[i];
  out[2 * i + 0] = a0 * inv + b2[0] + me.z;
  out[2 * i + 1] = a1 * inv + b2[1] + me.w;
}

// ---------------------------------------------------------------------------

extern "C" void kernel_launch(void* const* d_in, const int* in_sizes, int n_in,
                              void* d_out, int out_size, void* d_ws, size_t ws_size,
                              hipStream_t stream) {
  const float* x   = (const float*)d_in[0];
  const void*  eix = d_in[1];
  const float* W1l = (const float*)d_in[2];
  const float* b1  = (const float*)d_in[3];
  const float* W1r = (const float*)d_in[4];
  const float* W2l = (const float*)d_in[5];
  const float* b2  = (const float*)d_in[6];
  const float* W2r = (const float*)d_in[7];
  float* out = (float*)d_out;

  const int M  = in_sizes[0] / D_IN;       // 50000
  const int E  = in_sizes[1] / 2;          // 250000
  const int Mp = ((M + 127) / 128) * 128;  // 50048

  // workspace layout (256B aligned slots)
  char* ws = (char*)d_ws;
  size_t off = 0;
  auto alloc = [&](size_t b) { size_t o = off; off += (b + 255) & ~(size_t)255; return o; };
  size_t oFlag   = alloc(4);
  size_t oCounts = alloc((size_t)M * 4);
  size_t zeroBytes = oCounts + (size_t)M * 4;      // flag + counts
  size_t oOffs   = alloc((size_t)(M + 1) * 4);
  size_t oCursor = alloc((size_t)M * 4);
  size_t oCsr    = alloc((size_t)E * 4);
  size_t oSrc    = alloc((size_t)E * 4);
  size_t oDst    = alloc((size_t)E * 4);
  size_t oXb     = alloc((size_t)Mp * D_IN * 2);
  size_t oWb     = alloc((size_t)N1 * D_IN * 2);
  size_t oC      = alloc((size_t)Mp * N1 * 4);
  size_t oH      = alloc((size_t)M * D_HID * 4);
  size_t oRs     = alloc((size_t)M * 16);
  (void)ws_size; (void)n_in; (void)out_size;

  unsigned int* flag = (unsigned int*)(ws + oFlag);
  int* counts = (int*)(ws + oCounts);
  int* offs   = (int*)(ws + oOffs);
  int* cursor = (int*)(ws + oCursor);
  int* csr    = (int*)(ws + oCsr);
  int* src32  = (int*)(ws + oSrc);
  int* dst32  = (int*)(ws + oDst);
  unsigned short* xb = (unsigned short*)(ws + oXb);
  unsigned short* wb = (unsigned short*)(ws + oWb);
  float* C  = (float*)(ws + oC);
  float* h  = (float*)(ws + oH);
  float4* rs = (float4*)(ws + oRs);

  hipMemsetAsync(ws, 0, zeroBytes, stream);

  int gE = (E + 255) / 256;
  detect_k<<<gE, 256, 0, stream>>>((const unsigned int*)eix, flag, E);
  cvtidx_k<<<gE, 256, 0, stream>>>(eix, flag, src32, dst32, E);
  count_k<<<gE, 256, 0, stream>>>(dst32, counts, E);
  scan_k<<<1, 1024, 0, stream>>>(counts, offs, cursor, M);
  fill_k<<<gE, 256, 0, stream>>>(src32, dst32, cursor, csr, E);

  int gX = (Mp * (D_IN / 8) + 255) / 256;
  cvtx_k<<<gX, 256, 0, stream>>>(x, xb, M, Mp);
  int gW = (N1 * (D_IN / 8) + 255) / 256;
  cvtw_k<<<gW, 256, 0, stream>>>(W1l, W1r, wb);

  dim3 gg(Mp / 128, N1 / 128);
  gemm_k<<<gg, 256, 0, stream>>>(xb, wb, C, Mp);

  agg1_k<<<M, 256, 0, stream>>>(C, offs, csr, b1, h, M);
  l2_k<<<128, 256, 0, stream>>>(h, W2l, W2r, rs, M);
  final_k<<<(M + 255) / 256, 256, 0, stream>>>(rs, offs, csr, b2, out, M);
}

// Round 2
// 493.817 us; speedup vs baseline: 1.3059x; 1.3059x over previous
//
#include <hip/hip_runtime.h>
#include <stdint.h>

// ---------------------------------------------------------------------------
// GraphSAGE 2-layer: out = SAGE2(relu(SAGE1(x)))
// SAGE(x) = mean_agg(x@W_l.T) + b + x@W_r.T   (project-then-aggregate rewrite)
// R2: hierarchical scan (was 111us single-block), count fused into cvtidx,
//     wave-per-node agg1, bigger l2 grid.
// ---------------------------------------------------------------------------

#define D_IN  768
#define D_HID 256
#define N1    512   // concat(W1_l, W1_r) output width

typedef __attribute__((ext_vector_type(8))) short short8;
typedef __attribute__((ext_vector_type(4))) float f32x4;

__device__ __forceinline__ void async_copy16(const void* g, void* l) {
  __builtin_amdgcn_global_load_lds(
      (const __attribute__((address_space(1))) unsigned int*)g,
      (__attribute__((address_space(3))) unsigned int*)l,
      16, 0, 0);
}

__device__ __forceinline__ unsigned short f2bf(float f) {
  union { float f; unsigned u; } v; v.f = f;
  unsigned r = v.u + 0x7FFFu + ((v.u >> 16) & 1u);   // RNE
  return (unsigned short)(r >> 16);
}

// --------------------------- index handling --------------------------------

// If edge_index is int64 (LE), odd 32-bit words of the first E qwords are all 0.
__global__ void detect_k(const unsigned int* __restrict__ w,
                         unsigned int* __restrict__ flag, int E) {
  int i = blockIdx.x * 256 + threadIdx.x;
  unsigned v = (i < E) ? w[2 * i + 1] : 0u;
  unsigned long long any = __ballot(v != 0u);
  if ((threadIdx.x & 63) == 0 && any) atomicOr(flag, 1u);
}

// convert + count fused
__global__ void cvtidx_k(const void* __restrict__ eidx,
                         const unsigned int* __restrict__ flag,
                         int* __restrict__ src32, int* __restrict__ dst32,
                         int* __restrict__ counts, int E) {
  int i = blockIdx.x * 256 + threadIdx.x;
  if (i >= E) return;
  int s, d;
  if (*flag) {  // int32 data
    const int* p = (const int*)eidx;
    s = p[i]; d = p[E + i];
  } else {      // int64 data
    const long long* p = (const long long*)eidx;
    s = (int)p[i]; d = (int)p[E + i];
  }
  src32[i] = s;
  dst32[i] = d;
  atomicAdd(&counts[d], 1);
}

// ----- 3-phase hierarchical exclusive scan of counts[M] -> offs, cursor -----
// Phase A: per-block (1024 counts) reduce -> blockSums
__global__ void scanA_k(const int* __restrict__ counts,
                        int* __restrict__ blockSums, int M) {
  __shared__ int ts[256];
  int b = blockIdx.x, t = threadIdx.x;
  int base = b * 1024 + t * 4;
  int s = 0;
#pragma unroll
  for (int k = 0; k < 4; k++) { int i = base + k; if (i < M) s += counts[i]; }
  ts[t] = s;
  __syncthreads();
  for (int off = 128; off > 0; off >>= 1) {
    if (t < off) ts[t] += ts[t + off];
    __syncthreads();
  }
  if (t == 0) blockSums[b] = ts[0];
}

// Phase B: exclusive scan of blockSums (nb <= 64) in one wave
__global__ void scanB_k(const int* __restrict__ blockSums,
                        int* __restrict__ blockOffs, int nb) {
  int t = threadIdx.x;   // 64 threads
  int v = (t < nb) ? blockSums[t] : 0;
  int orig = v;
#pragma unroll
  for (int off = 1; off < 64; off <<= 1) {
    int u = __shfl_up(v, off);
    if (t >= off) v += u;
  }
  if (t < nb) blockOffs[t] = v - orig;   // exclusive
}

// Phase C: local scan + block offset -> offs[i], cursor[i]; offs[M]=E
__global__ void scanC_k(const int* __restrict__ counts,
                        const int* __restrict__ blockOffs,
                        int* __restrict__ offs, int* __restrict__ cursor,
                        int M, int E) {
  __shared__ int ts[256];
  int b = blockIdx.x, t = threadIdx.x;
  int base = b * 1024 + t * 4;
  int v[4]; int s = 0;
#pragma unroll
  for (int k = 0; k < 4; k++) {
    int i = base + k;
    v[k] = (i < M) ? counts[i] : 0;
    s += v[k];
  }
  ts[t] = s;
  __syncthreads();
  for (int off = 1; off < 256; off <<= 1) {
    int x = (t >= off) ? ts[t - off] : 0;
    __syncthreads();
    ts[t] += x;
    __syncthreads();
  }
  int run = blockOffs[b] + ts[t] - s;   // exclusive prefix for this thread
#pragma unroll
  for (int k = 0; k < 4; k++) {
    int i = base + k;
    if (i < M) { offs[i] = run; cursor[i] = run; run += v[k]; }
  }
  if (b == 0 && t == 0) offs[M] = E;
}

__global__ void fill_k(const int* __restrict__ src, const int* __restrict__ dst,
                       int* __restrict__ cursor, int* __restrict__ csr, int E) {
  int i = blockIdx.x * 256 + threadIdx.x;
  if (i >= E) return;
  int pos = atomicAdd(&cursor[dst[i]], 1);
  csr[pos] = src[i];
}

// --------------------------- bf16 conversion -------------------------------

// 8 elements per thread; rows >= M are zero padding.
__global__ void cvtx_k(const float* __restrict__ x, unsigned short* __restrict__ xb,
                       int M, int Mp) {
  int idx = blockIdx.x * 256 + threadIdx.x;   // chunk of 8 elements
  int total = Mp * (D_IN / 8);
  if (idx >= total) return;
  int row = idx / (D_IN / 8);
  int cpos = (idx % (D_IN / 8)) * 8;
  short8 o;
  if (row < M) {
    const float* p = x + (size_t)row * D_IN + cpos;
    float4 f0 = *(const float4*)p;
    float4 f1 = *(const float4*)(p + 4);
    o[0] = (short)f2bf(f0.x); o[1] = (short)f2bf(f0.y);
    o[2] = (short)f2bf(f0.z); o[3] = (short)f2bf(f0.w);
    o[4] = (short)f2bf(f1.x); o[5] = (short)f2bf(f1.y);
    o[6] = (short)f2bf(f1.z); o[7] = (short)f2bf(f1.w);
  } else {
    o = (short8)0;
  }
  *(short8*)(xb + (size_t)idx * 8) = o;
}

// wb rows 0..255 = W1_l, 256..511 = W1_r  (each [256,768])
__global__ void cvtw_k(const float* __restrict__ W1l, const float* __restrict__ W1r,
                       unsigned short* __restrict__ wb) {
  int idx = blockIdx.x * 256 + threadIdx.x;   // chunk of 8
  int total = N1 * (D_IN / 8);
  if (idx >= total) return;
  int row = idx / (D_IN / 8);
  int cpos = (idx % (D_IN / 8)) * 8;
  const float* p = (row < D_HID) ? (W1l + (size_t)row * D_IN + cpos)
                                 : (W1r + (size_t)(row - D_HID) * D_IN + cpos);
  float4 f0 = *(const float4*)p;
  float4 f1 = *(const float4*)(p + 4);
  short8 o;
  o[0] = (short)f2bf(f0.x); o[1] = (short)f2bf(f0.y);
  o[2] = (short)f2bf(f0.z); o[3] = (short)f2bf(f0.w);
  o[4] = (short)f2bf(f1.x); o[5] = (short)f2bf(f1.y);
  o[6] = (short)f2bf(f1.z); o[7] = (short)f2bf(f1.w);
  *(short8*)(wb + (size_t)idx * 8) = o;
}

// --------------------------- layer-1 GEMM ----------------------------------
// C[Mp, 512] = xb[Mp, 768] @ wb[512, 768]^T   (bf16 inputs, fp32 out)
// 128x128 tile, BK=32, 4 waves, each wave 64x64 via 4x4 of 16x16x32 MFMA.
__global__ __launch_bounds__(256) void gemm_k(
    const unsigned short* __restrict__ xb,
    const unsigned short* __restrict__ wb,
    float* __restrict__ C, int Mp) {
  __shared__ unsigned short As[128 * 32];
  __shared__ unsigned short Bs[128 * 32];
  const int tid  = threadIdx.x;
  const int lane = tid & 63;
  const int wid  = tid >> 6;
  const int wr = wid >> 1, wc = wid & 1;
  const int m0 = blockIdx.x * 128;
  const int n0 = blockIdx.y * 128;
  const int l15  = lane & 15;
  const int quad = lane >> 4;

  f32x4 acc[4][4];
#pragma unroll
  for (int r = 0; r < 4; r++)
#pragma unroll
    for (int c = 0; c < 4; c++) acc[r][c] = (f32x4)0.0f;

  for (int k0 = 0; k0 < D_IN; k0 += 32) {
    __syncthreads();   // previous iteration's LDS reads done
#pragma unroll
    for (int l = 0; l < 4; ++l) {
      int chunk = l * 256 + tid;            // 0..1023; wave-uniform A/B split
      if (chunk < 512) {
        int row = chunk >> 2, cg = chunk & 3;
        async_copy16(xb + (size_t)(m0 + row) * D_IN + k0 + cg * 8, &As[chunk * 8]);
      } else {
        int cb = chunk - 512;
        int row = cb >> 2, cg = cb & 3;
        async_copy16(wb + (size_t)(n0 + row) * D_IN + k0 + cg * 8, &Bs[cb * 8]);
      }
    }
    __syncthreads();   // staging drained

    short8 a[4], b[4];
#pragma unroll
    for (int r = 0; r < 4; r++)
      a[r] = *(const short8*)&As[(wr * 64 + r * 16 + l15) * 32 + quad * 8];
#pragma unroll
    for (int c = 0; c < 4; c++)
      b[c] = *(const short8*)&Bs[(wc * 64 + c * 16 + l15) * 32 + quad * 8];
#pragma unroll
    for (int r = 0; r < 4; r++)
#pragma unroll
      for (int c = 0; c < 4; c++)
        acc[r][c] = __builtin_amdgcn_mfma_f32_16x16x32_bf16(a[r], b[c], acc[r][c], 0, 0, 0);
  }

  // epilogue: C/D layout col=lane&15, row=(lane>>4)*4+reg
  const int crow0 = m0 + wr * 64;
  const int ccol0 = n0 + wc * 64;
#pragma unroll
  for (int r = 0; r < 4; r++)
#pragma unroll
    for (int c = 0; c < 4; c++) {
      int col = ccol0 + c * 16 + l15;
#pragma unroll
      for (int reg = 0; reg < 4; reg++) {
        int row = crow0 + r * 16 + quad * 4 + reg;
        C[(size_t)row * N1 + col] = acc[r][c][reg];
      }
    }
}

// --------------------------- layer-1 aggregate + epilogue ------------------
// h[i][c] = relu( mean_{j in N(i)} C[j][c] + b1[c] + C[i][256+c] )
// wave per node, grid-stride; lane covers 4 columns (float4).
__global__ void agg1_k(const float* __restrict__ C, const int* __restrict__ offs,
                       const int* __restrict__ csr, const float* __restrict__ b1,
                       float* __restrict__ h, int M) {
  int tid = threadIdx.x;
  int lane = tid & 63;
  int wid = tid >> 6;
  int wave = blockIdx.x * 4 + wid;
  int nw = gridDim.x * 4;
  int c = lane * 4;
  float4 bv = *(const float4*)(b1 + c);
  for (int i = wave; i < M; i += nw) {
    int s = offs[i], e = offs[i + 1];
    float ax = 0.f, ay = 0.f, az = 0.f, aw = 0.f;
    for (int t = s; t < e; t++) {
      int j = csr[t];
      float4 v = *(const float4*)(C + (size_t)j * N1 + c);
      ax += v.x; ay += v.y; az += v.z; aw += v.w;
    }
    float inv = 1.0f / fmaxf((float)(e - s), 1.0f);
    float4 own = *(const float4*)(C + (size_t)i * N1 + D_HID + c);
    float4 o;
    o.x = fmaxf(ax * inv + bv.x + own.x, 0.0f);
    o.y = fmaxf(ay * inv + bv.y + own.y, 0.0f);
    o.z = fmaxf(az * inv + bv.z + own.z, 0.0f);
    o.w = fmaxf(aw * inv + bv.w + own.w, 0.0f);
    *(float4*)(h + (size_t)i * D_HID + c) = o;
  }
}

// --------------------------- layer-2 GEMV ----------------------------------
// rs[i] = { h[i]@W2_l[0], h[i]@W2_l[1], h[i]@W2_r[0], h[i]@W2_r[1] }
__global__ void l2_k(const float* __restrict__ h, const float* __restrict__ W2l,
                     const float* __restrict__ W2r, float4* __restrict__ rs, int M) {
  int tid = threadIdx.x;
  int lane = tid & 63;
  int wid = tid >> 6;
  int wave = blockIdx.x * 4 + wid;
  int nw = gridDim.x * 4;
  int c = lane * 4;
  float4 wl0 = *(const float4*)(W2l + c);
  float4 wl1 = *(const float4*)(W2l + D_HID + c);
  float4 wr0 = *(const float4*)(W2r + c);
  float4 wr1 = *(const float4*)(W2r + D_HID + c);
  for (int i = wave; i < M; i += nw) {
    float4 hv = *(const float4*)(h + (size_t)i * D_HID + c);
    float r0 = hv.x * wl0.x + hv.y * wl0.y + hv.z * wl0.z + hv.w * wl0.w;
    float r1 = hv.x * wl1.x + hv.y * wl1.y + hv.z * wl1.z + hv.w * wl1.w;
    float s0 = hv.x * wr0.x + hv.y * wr0.y + hv.z * wr0.z + hv.w * wr0.w;
    float s1 = hv.x * wr1.x + hv.y * wr1.y + hv.z * wr1.z + hv.w * wr1.w;
#pragma unroll
    for (int off = 32; off > 0; off >>= 1) {
      r0 += __shfl_xor(r0, off);
      r1 += __shfl_xor(r1, off);
      s0 += __shfl_xor(s0, off);
      s1 += __shfl_xor(s1, off);
    }
    if (lane == 0) rs[i] = make_float4(r0, r1, s0, s1);
  }
}

// --------------------------- final -----------------------------------------
// out[i][j] = mean_{k in N(i)} rs[k][j] + b2[j] + rs[i][2+j]
__global__ void final_k(const float4* __restrict__ rs, const int* __restrict__ offs,
                        const int* __restrict__ csr, const float* __restrict__ b2,
                        float* __restrict__ out, int M) {
  int i = blockIdx.x * 256 + threadIdx.x;
  if (i >= M) return;
  int s = offs[i], e = offs[i + 1];
  float a0 = 0.0f, a1 = 0.0f;
  for (int t = s; t < e; t++) {
    float4 v = rs[csr[t]];
    a0 += v.x; a1 += v.y;
  }
  float inv = 1.0f / fmaxf((float)(e - s), 1.0f);
  float4 me = rs[i];
  out[2 * i + 0] = a0 * inv + b2[0] + me.z;
  out[2 * i + 1] = a1 * inv + b2[1] + me.w;
}

// ---------------------------------------------------------------------------

extern "C" void kernel_launch(void* const* d_in, const int* in_sizes, int n_in,
                              void* d_out, int out_size, void* d_ws, size_t ws_size,
                              hipStream_t stream) {
  const float* x   = (const float*)d_in[0];
  const void*  eix = d_in[1];
  const float* W1l = (const float*)d_in[2];
  const float* b1  = (const float*)d_in[3];
  const float* W1r = (const float*)d_in[4];
  const float* W2l = (const float*)d_in[5];
  const float* b2  = (const float*)d_in[6];
  const float* W2r = (const float*)d_in[7];
  float* out = (float*)d_out;

  const int M  = in_sizes[0] / D_IN;       // 50000
  const int E  = in_sizes[1] / 2;          // 250000
  const int Mp = ((M + 127) / 128) * 128;  // 50048
  const int nb = (M + 1023) / 1024;        // scan blocks (<=64)

  // workspace layout (256B aligned slots)
  char* ws = (char*)d_ws;
  size_t off = 0;
  auto alloc = [&](size_t b) { size_t o = off; off += (b + 255) & ~(size_t)255; return o; };
  size_t oFlag   = alloc(4);
  size_t oCounts = alloc((size_t)M * 4);
  size_t zeroBytes = oCounts + (size_t)M * 4;      // flag + counts
  size_t oOffs   = alloc((size_t)(M + 1) * 4);
  size_t oCursor = alloc((size_t)M * 4);
  size_t oCsr    = alloc((size_t)E * 4);
  size_t oSrc    = alloc((size_t)E * 4);
  size_t oDst    = alloc((size_t)E * 4);
  size_t oBSums  = alloc(64 * 4);
  size_t oBOffs  = alloc(64 * 4);
  size_t oXb     = alloc((size_t)Mp * D_IN * 2);
  size_t oWb     = alloc((size_t)N1 * D_IN * 2);
  size_t oC      = alloc((size_t)Mp * N1 * 4);
  size_t oH      = alloc((size_t)M * D_HID * 4);
  size_t oRs     = alloc((size_t)M * 16);
  (void)ws_size; (void)n_in; (void)out_size;

  unsigned int* flag = (unsigned int*)(ws + oFlag);
  int* counts = (int*)(ws + oCounts);
  int* offs   = (int*)(ws + oOffs);
  int* cursor = (int*)(ws + oCursor);
  int* csr    = (int*)(ws + oCsr);
  int* src32  = (int*)(ws + oSrc);
  int* dst32  = (int*)(ws + oDst);
  int* bsums  = (int*)(ws + oBSums);
  int* boffs  = (int*)(ws + oBOffs);
  unsigned short* xb = (unsigned short*)(ws + oXb);
  unsigned short* wb = (unsigned short*)(ws + oWb);
  float* C  = (float*)(ws + oC);
  float* h  = (float*)(ws + oH);
  float4* rs = (float4*)(ws + oRs);

  hipMemsetAsync(ws, 0, zeroBytes, stream);

  int gE = (E + 255) / 256;
  detect_k<<<gE, 256, 0, stream>>>((const unsigned int*)eix, flag, E);
  cvtidx_k<<<gE, 256, 0, stream>>>(eix, flag, src32, dst32, counts, E);
  scanA_k<<<nb, 256, 0, stream>>>(counts, bsums, M);
  scanB_k<<<1, 64, 0, stream>>>(bsums, boffs, nb);
  scanC_k<<<nb, 256, 0, stream>>>(counts, boffs, offs, cursor, M, E);
  fill_k<<<gE, 256, 0, stream>>>(src32, dst32, cursor, csr, E);

  int gX = (Mp * (D_IN / 8) + 255) / 256;
  cvtx_k<<<gX, 256, 0, stream>>>(x, xb, M, Mp);
  int gW = (N1 * (D_IN / 8) + 255) / 256;
  cvtw_k<<<gW, 256, 0, stream>>>(W1l, W1r, wb);

  dim3 gg(Mp / 128, N1 / 128);
  gemm_k<<<gg, 256, 0, stream>>>(xb, wb, C, Mp);

  agg1_k<<<1024, 256, 0, stream>>>(C, offs, csr, b1, h, M);
  l2_k<<<512, 256, 0, stream>>>(h, W2l, W2r, rs, M);
  final_k<<<(M + 255) / 256, 256, 0, stream>>>(rs, offs, csr, b2, out, M);
}

// Round 3
// 456.845 us; speedup vs baseline: 1.4116x; 1.0809x over previous
//
#include <hip/hip_runtime.h>
#include <stdint.h>

// ---------------------------------------------------------------------------
// GraphSAGE 2-layer: out = SAGE2(relu(SAGE1(x)))
// SAGE(x) = mean_agg(x@W_l.T) + b + x@W_r.T   (project-then-aggregate rewrite)
// R3: K-major LDS segments in gemm (bank-conflict-free frag reads),
//     bf16 C output (half write + half gather traffic), l2 fused into agg1.
// ---------------------------------------------------------------------------

#define D_IN  768
#define D_HID 256
#define N1    512   // concat(W1_l, W1_r) output width

typedef __attribute__((ext_vector_type(8))) short short8;
typedef __attribute__((ext_vector_type(4))) float f32x4;

__device__ __forceinline__ void async_copy16(const void* g, void* l) {
  __builtin_amdgcn_global_load_lds(
      (const __attribute__((address_space(1))) unsigned int*)g,
      (__attribute__((address_space(3))) unsigned int*)l,
      16, 0, 0);
}

__device__ __forceinline__ unsigned short f2bf(float f) {
  union { float f; unsigned u; } v; v.f = f;
  unsigned r = v.u + 0x7FFFu + ((v.u >> 16) & 1u);   // RNE
  return (unsigned short)(r >> 16);
}

__device__ __forceinline__ float bf2f(unsigned short b) {
  union { unsigned u; float f; } v; v.u = ((unsigned)b) << 16;
  return v.f;
}

// --------------------------- index handling --------------------------------

// If edge_index is int64 (LE), odd 32-bit words of the first E qwords are all 0.
__global__ void detect_k(const unsigned int* __restrict__ w,
                         unsigned int* __restrict__ flag, int E) {
  int i = blockIdx.x * 256 + threadIdx.x;
  unsigned v = (i < E) ? w[2 * i + 1] : 0u;
  unsigned long long any = __ballot(v != 0u);
  if ((threadIdx.x & 63) == 0 && any) atomicOr(flag, 1u);
}

// convert + count fused
__global__ void cvtidx_k(const void* __restrict__ eidx,
                         const unsigned int* __restrict__ flag,
                         int* __restrict__ src32, int* __restrict__ dst32,
                         int* __restrict__ counts, int E) {
  int i = blockIdx.x * 256 + threadIdx.x;
  if (i >= E) return;
  int s, d;
  if (*flag) {  // int32 data
    const int* p = (const int*)eidx;
    s = p[i]; d = p[E + i];
  } else {      // int64 data
    const long long* p = (const long long*)eidx;
    s = (int)p[i]; d = (int)p[E + i];
  }
  src32[i] = s;
  dst32[i] = d;
  atomicAdd(&counts[d], 1);
}

// ----- 3-phase hierarchical exclusive scan of counts[M] -> offs, cursor -----
__global__ void scanA_k(const int* __restrict__ counts,
                        int* __restrict__ blockSums, int M) {
  __shared__ int ts[256];
  int b = blockIdx.x, t = threadIdx.x;
  int base = b * 1024 + t * 4;
  int s = 0;
#pragma unroll
  for (int k = 0; k < 4; k++) { int i = base + k; if (i < M) s += counts[i]; }
  ts[t] = s;
  __syncthreads();
  for (int off = 128; off > 0; off >>= 1) {
    if (t < off) ts[t] += ts[t + off];
    __syncthreads();
  }
  if (t == 0) blockSums[b] = ts[0];
}

__global__ void scanB_k(const int* __restrict__ blockSums,
                        int* __restrict__ blockOffs, int nb) {
  int t = threadIdx.x;   // 64 threads
  int v = (t < nb) ? blockSums[t] : 0;
  int orig = v;
#pragma unroll
  for (int off = 1; off < 64; off <<= 1) {
    int u = __shfl_up(v, off);
    if (t >= off) v += u;
  }
  if (t < nb) blockOffs[t] = v - orig;   // exclusive
}

__global__ void scanC_k(const int* __restrict__ counts,
                        const int* __restrict__ blockOffs,
                        int* __restrict__ offs, int* __restrict__ cursor,
                        int M, int E) {
  __shared__ int ts[256];
  int b = blockIdx.x, t = threadIdx.x;
  int base = b * 1024 + t * 4;
  int v[4]; int s = 0;
#pragma unroll
  for (int k = 0; k < 4; k++) {
    int i = base + k;
    v[k] = (i < M) ? counts[i] : 0;
    s += v[k];
  }
  ts[t] = s;
  __syncthreads();
  for (int off = 1; off < 256; off <<= 1) {
    int x = (t >= off) ? ts[t - off] : 0;
    __syncthreads();
    ts[t] += x;
    __syncthreads();
  }
  int run = blockOffs[b] + ts[t] - s;
#pragma unroll
  for (int k = 0; k < 4; k++) {
    int i = base + k;
    if (i < M) { offs[i] = run; cursor[i] = run; run += v[k]; }
  }
  if (b == 0 && t == 0) offs[M] = E;
}

__global__ void fill_k(const int* __restrict__ src, const int* __restrict__ dst,
                       int* __restrict__ cursor, int* __restrict__ csr, int E) {
  int i = blockIdx.x * 256 + threadIdx.x;
  if (i >= E) return;
  int pos = atomicAdd(&cursor[dst[i]], 1);
  csr[pos] = src[i];
}

// --------------------------- bf16 conversion -------------------------------

__global__ void cvtx_k(const float* __restrict__ x, unsigned short* __restrict__ xb,
                       int M, int Mp) {
  int idx = blockIdx.x * 256 + threadIdx.x;   // chunk of 8 elements
  int total = Mp * (D_IN / 8);
  if (idx >= total) return;
  int row = idx / (D_IN / 8);
  int cpos = (idx % (D_IN / 8)) * 8;
  short8 o;
  if (row < M) {
    const float* p = x + (size_t)row * D_IN + cpos;
    float4 f0 = *(const float4*)p;
    float4 f1 = *(const float4*)(p + 4);
    o[0] = (short)f2bf(f0.x); o[1] = (short)f2bf(f0.y);
    o[2] = (short)f2bf(f0.z); o[3] = (short)f2bf(f0.w);
    o[4] = (short)f2bf(f1.x); o[5] = (short)f2bf(f1.y);
    o[6] = (short)f2bf(f1.z); o[7] = (short)f2bf(f1.w);
  } else {
    o = (short8)0;
  }
  *(short8*)(xb + (size_t)idx * 8) = o;
}

// wb rows 0..255 = W1_l, 256..511 = W1_r  (each [256,768])
__global__ void cvtw_k(const float* __restrict__ W1l, const float* __restrict__ W1r,
                       unsigned short* __restrict__ wb) {
  int idx = blockIdx.x * 256 + threadIdx.x;   // chunk of 8
  int total = N1 * (D_IN / 8);
  if (idx >= total) return;
  int row = idx / (D_IN / 8);
  int cpos = (idx % (D_IN / 8)) * 8;
  const float* p = (row < D_HID) ? (W1l + (size_t)row * D_IN + cpos)
                                 : (W1r + (size_t)(row - D_HID) * D_IN + cpos);
  float4 f0 = *(const float4*)p;
  float4 f1 = *(const float4*)(p + 4);
  short8 o;
  o[0] = (short)f2bf(f0.x); o[1] = (short)f2bf(f0.y);
  o[2] = (short)f2bf(f0.z); o[3] = (short)f2bf(f0.w);
  o[4] = (short)f2bf(f1.x); o[5] = (short)f2bf(f1.y);
  o[6] = (short)f2bf(f1.z); o[7] = (short)f2bf(f1.w);
  *(short8*)(wb + (size_t)idx * 8) = o;
}

// --------------------------- layer-1 GEMM ----------------------------------
// Cb[Mp, 512](bf16) = xb[Mp, 768] @ wb[512, 768]^T
// 128x128 tile, BK=32, 4 waves, each wave 64x64 via 4x4 of 16x16x32 MFMA.
// LDS layout: 8 segments of 1024B per operand; segment s holds rows
// [16s,16s+16) x 32 k, stored K-major: chunk(row,cg) at s*1024 + cg*256 +
// (row&15)*16. Frag reads then stride 16B across lanes -> conflict-free.
__global__ __launch_bounds__(256) void gemm_k(
    const unsigned short* __restrict__ xb,
    const unsigned short* __restrict__ wb,
    unsigned short* __restrict__ Cb, int Mp) {
  __shared__ unsigned short As[128 * 32];
  __shared__ unsigned short Bs[128 * 32];
  const int tid  = threadIdx.x;
  const int lane = tid & 63;
  const int wid  = tid >> 6;
  const int wr = wid >> 1, wc = wid & 1;
  const int m0 = blockIdx.x * 128;
  const int n0 = blockIdx.y * 128;
  const int l15  = lane & 15;
  const int quad = lane >> 4;

  f32x4 acc[4][4];
#pragma unroll
  for (int r = 0; r < 4; r++)
#pragma unroll
    for (int c = 0; c < 4; c++) acc[r][c] = (f32x4)0.0f;

  for (int k0 = 0; k0 < D_IN; k0 += 32) {
    __syncthreads();   // previous iteration's LDS reads done
#pragma unroll
    for (int l = 0; l < 4; ++l) {
      int chunk = l * 256 + tid;            // 0..1023; one segment per wave
      if (chunk < 512) {
        int row = (chunk >> 6) * 16 + (chunk & 15);   // K-major within segment
        int cg  = (chunk >> 4) & 3;
        async_copy16(xb + (size_t)(m0 + row) * D_IN + k0 + cg * 8, &As[chunk * 8]);
      } else {
        int cb = chunk - 512;
        int row = (cb >> 6) * 16 + (cb & 15);
        int cg  = (cb >> 4) & 3;
        async_copy16(wb + (size_t)(n0 + row) * D_IN + k0 + cg * 8, &Bs[cb * 8]);
      }
    }
    __syncthreads();   // staging drained

    short8 a[4], b[4];
#pragma unroll
    for (int r = 0; r < 4; r++)
      a[r] = *(const short8*)&As[(wr * 4 + r) * 512 + quad * 128 + l15 * 8];
#pragma unroll
    for (int c = 0; c < 4; c++)
      b[c] = *(const short8*)&Bs[(wc * 4 + c) * 512 + quad * 128 + l15 * 8];
#pragma unroll
    for (int r = 0; r < 4; r++)
#pragma unroll
      for (int c = 0; c < 4; c++)
        acc[r][c] = __builtin_amdgcn_mfma_f32_16x16x32_bf16(a[r], b[c], acc[r][c], 0, 0, 0);
  }

  // epilogue: C/D layout col=lane&15, row=(lane>>4)*4+reg; store bf16
  const int crow0 = m0 + wr * 64;
  const int ccol0 = n0 + wc * 64;
#pragma unroll
  for (int r = 0; r < 4; r++)
#pragma unroll
    for (int c = 0; c < 4; c++) {
      int col = ccol0 + c * 16 + l15;
#pragma unroll
      for (int reg = 0; reg < 4; reg++) {
        int row = crow0 + r * 16 + quad * 4 + reg;
        Cb[(size_t)row * N1 + col] = f2bf(acc[r][c][reg]);
      }
    }
}

// --------------------- fused aggregate + epilogue + layer-2 ----------------
// h[c] = relu( mean_{j in N(i)} Cb[j][c] + b1[c] + Cb[i][256+c] )  (registers)
// rs[i] = { h@W2_l[0], h@W2_l[1], h@W2_r[0], h@W2_r[1] }
__global__ void agg_l2_k(const unsigned short* __restrict__ Cb,
                         const int* __restrict__ offs, const int* __restrict__ csr,
                         const float* __restrict__ b1,
                         const float* __restrict__ W2l, const float* __restrict__ W2r,
                         float4* __restrict__ rs, int M) {
  int tid = threadIdx.x;
  int lane = tid & 63;
  int wid = tid >> 6;
  int wave = blockIdx.x * 4 + wid;
  int nw = gridDim.x * 4;
  int c = lane * 4;
  float4 bv  = *(const float4*)(b1 + c);
  float4 wl0 = *(const float4*)(W2l + c);
  float4 wl1 = *(const float4*)(W2l + D_HID + c);
  float4 wr0 = *(const float4*)(W2r + c);
  float4 wr1 = *(const float4*)(W2r + D_HID + c);
  for (int i = wave; i < M; i += nw) {
    int s = offs[i], e = offs[i + 1];
    float ax = 0.f, ay = 0.f, az = 0.f, aw = 0.f;
    for (int t = s; t < e; t++) {
      int j = csr[t];
      ushort4 v = *(const ushort4*)(Cb + (size_t)j * N1 + c);
      ax += bf2f(v.x); ay += bf2f(v.y); az += bf2f(v.z); aw += bf2f(v.w);
    }
    float inv = 1.0f / fmaxf((float)(e - s), 1.0f);
    ushort4 q = *(const ushort4*)(Cb + (size_t)i * N1 + D_HID + c);
    float h0 = fmaxf(ax * inv + bv.x + bf2f(q.x), 0.0f);
    float h1 = fmaxf(ay * inv + bv.y + bf2f(q.y), 0.0f);
    float h2 = fmaxf(az * inv + bv.z + bf2f(q.z), 0.0f);
    float h3 = fmaxf(aw * inv + bv.w + bf2f(q.w), 0.0f);
    float r0 = h0 * wl0.x + h1 * wl0.y + h2 * wl0.z + h3 * wl0.w;
    float r1 = h0 * wl1.x + h1 * wl1.y + h2 * wl1.z + h3 * wl1.w;
    float s0 = h0 * wr0.x + h1 * wr0.y + h2 * wr0.z + h3 * wr0.w;
    float s1 = h0 * wr1.x + h1 * wr1.y + h2 * wr1.z + h3 * wr1.w;
#pragma unroll
    for (int off = 32; off > 0; off >>= 1) {
      r0 += __shfl_xor(r0, off);
      r1 += __shfl_xor(r1, off);
      s0 += __shfl_xor(s0, off);
      s1 += __shfl_xor(s1, off);
    }
    if (lane == 0) rs[i] = make_float4(r0, r1, s0, s1);
  }
}

// --------------------------- final -----------------------------------------
// out[i][j] = mean_{k in N(i)} rs[k][j] + b2[j] + rs[i][2+j]
__global__ void final_k(const float4* __restrict__ rs, const int* __restrict__ offs,
                        const int* __restrict__ csr, const float* __restrict__ b2,
                        float* __restrict__ out, int M) {
  int i = blockIdx.x * 256 + threadIdx.x;
  if (i >= M) return;
  int s = offs[i], e = offs[i + 1];
  float a0 = 0.0f, a1 = 0.0f;
  for (int t = s; t < e; t++) {
    float4 v = rs[csr[t]];
    a0 += v.x; a1 += v.y;
  }
  float inv = 1.0f / fmaxf((float)(e - s), 1.0f);
  float4 me = rs[i];
  out[2 * i + 0] = a0 * inv + b2[0] + me.z;
  out[2 * i + 1] = a1 * inv + b2[1] + me.w;
}

// ---------------------------------------------------------------------------

extern "C" void kernel_launch(void* const* d_in, const int* in_sizes, int n_in,
                              void* d_out, int out_size, void* d_ws, size_t ws_size,
                              hipStream_t stream) {
  const float* x   = (const float*)d_in[0];
  const void*  eix = d_in[1];
  const float* W1l = (const float*)d_in[2];
  const float* b1  = (const float*)d_in[3];
  const float* W1r = (const float*)d_in[4];
  const float* W2l = (const float*)d_in[5];
  const float* b2  = (const float*)d_in[6];
  const float* W2r = (const float*)d_in[7];
  float* out = (float*)d_out;

  const int M  = in_sizes[0] / D_IN;       // 50000
  const int E  = in_sizes[1] / 2;          // 250000
  const int Mp = ((M + 127) / 128) * 128;  // 50048
  const int nb = (M + 1023) / 1024;        // scan blocks (<=64)

  // workspace layout (256B aligned slots)
  char* ws = (char*)d_ws;
  size_t off = 0;
  auto alloc = [&](size_t b) { size_t o = off; off += (b + 255) & ~(size_t)255; return o; };
  size_t oFlag   = alloc(4);
  size_t oCounts = alloc((size_t)M * 4);
  size_t zeroBytes = oCounts + (size_t)M * 4;      // flag + counts
  size_t oOffs   = alloc((size_t)(M + 1) * 4);
  size_t oCursor = alloc((size_t)M * 4);
  size_t oCsr    = alloc((size_t)E * 4);
  size_t oSrc    = alloc((size_t)E * 4);
  size_t oDst    = alloc((size_t)E * 4);
  size_t oBSums  = alloc(64 * 4);
  size_t oBOffs  = alloc(64 * 4);
  size_t oXb     = alloc((size_t)Mp * D_IN * 2);
  size_t oWb     = alloc((size_t)N1 * D_IN * 2);
  size_t oC      = alloc((size_t)Mp * N1 * 2);     // bf16 now
  size_t oRs     = alloc((size_t)M * 16);
  (void)ws_size; (void)n_in; (void)out_size;

  unsigned int* flag = (unsigned int*)(ws + oFlag);
  int* counts = (int*)(ws + oCounts);
  int* offs   = (int*)(ws + oOffs);
  int* cursor = (int*)(ws + oCursor);
  int* csr    = (int*)(ws + oCsr);
  int* src32  = (int*)(ws + oSrc);
  int* dst32  = (int*)(ws + oDst);
  int* bsums  = (int*)(ws + oBSums);
  int* boffs  = (int*)(ws + oBOffs);
  unsigned short* xb = (unsigned short*)(ws + oXb);
  unsigned short* wb = (unsigned short*)(ws + oWb);
  unsigned short* Cb = (unsigned short*)(ws + oC);
  float4* rs = (float4*)(ws + oRs);

  hipMemsetAsync(ws, 0, zeroBytes, stream);

  int gE = (E + 255) / 256;
  detect_k<<<gE, 256, 0, stream>>>((const unsigned int*)eix, flag, E);
  cvtidx_k<<<gE, 256, 0, stream>>>(eix, flag, src32, dst32, counts, E);
  scanA_k<<<nb, 256, 0, stream>>>(counts, bsums, M);
  scanB_k<<<1, 64, 0, stream>>>(bsums, boffs, nb);
  scanC_k<<<nb, 256, 0, stream>>>(counts, boffs, offs, cursor, M, E);
  fill_k<<<gE, 256, 0, stream>>>(src32, dst32, cursor, csr, E);

  int gX = (Mp * (D_IN / 8) + 255) / 256;
  cvtx_k<<<gX, 256, 0, stream>>>(x, xb, M, Mp);
  int gW = (N1 * (D_IN / 8) + 255) / 256;
  cvtw_k<<<gW, 256, 0, stream>>>(W1l, W1r, wb);

  dim3 gg(Mp / 128, N1 / 128);
  gemm_k<<<gg, 256, 0, stream>>>(xb, wb, Cb, Mp);

  agg_l2_k<<<2048, 256, 0, stream>>>(Cb, offs, csr, b1, W2l, W2r, rs, M);
  final_k<<<(M + 255) / 256, 256, 0, stream>>>(rs, offs, csr, b2, out, M);
}

// Round 4
// 435.246 us; speedup vs baseline: 1.4816x; 1.0496x over previous
//
#include <hip/hip_runtime.h>
#include <stdint.h>

// ---------------------------------------------------------------------------
// GraphSAGE 2-layer: out = SAGE2(relu(SAGE1(x)))
// SAGE(x) = mean_agg(x@W_l.T) + b + x@W_r.T   (project-then-aggregate rewrite)
// R4: cvtx fused into gemm (explicit fp32->bf16 A staging), grid swapped so
//     A-tile's 4 n-blocks are dispatch-adjacent (L2/L3 reuse), scanB folded
//     into scanC. LDS frag reads remain conflict-free (K-major segments).
// ---------------------------------------------------------------------------

#define D_IN  768
#define D_HID 256
#define N1    512   // concat(W1_l, W1_r) output width

typedef __attribute__((ext_vector_type(8))) short short8;
typedef __attribute__((ext_vector_type(4))) float f32x4;

__device__ __forceinline__ void async_copy16(const void* g, void* l) {
  __builtin_amdgcn_global_load_lds(
      (const __attribute__((address_space(1))) unsigned int*)g,
      (__attribute__((address_space(3))) unsigned int*)l,
      16, 0, 0);
}

__device__ __forceinline__ unsigned short f2bf(float f) {
  union { float f; unsigned u; } v; v.f = f;
  unsigned r = v.u + 0x7FFFu + ((v.u >> 16) & 1u);   // RNE
  return (unsigned short)(r >> 16);
}

__device__ __forceinline__ float bf2f(unsigned short b) {
  union { unsigned u; float f; } v; v.u = ((unsigned)b) << 16;
  return v.f;
}

// --------------------------- index handling --------------------------------

// If edge_index is int64 (LE), odd 32-bit words of the first E qwords are all 0.
__global__ void detect_k(const unsigned int* __restrict__ w,
                         unsigned int* __restrict__ flag, int E) {
  int i = blockIdx.x * 256 + threadIdx.x;
  unsigned v = (i < E) ? w[2 * i + 1] : 0u;
  unsigned long long any = __ballot(v != 0u);
  if ((threadIdx.x & 63) == 0 && any) atomicOr(flag, 1u);
}

// convert + count fused
__global__ void cvtidx_k(const void* __restrict__ eidx,
                         const unsigned int* __restrict__ flag,
                         int* __restrict__ src32, int* __restrict__ dst32,
                         int* __restrict__ counts, int E) {
  int i = blockIdx.x * 256 + threadIdx.x;
  if (i >= E) return;
  int s, d;
  if (*flag) {  // int32 data
    const int* p = (const int*)eidx;
    s = p[i]; d = p[E + i];
  } else {      // int64 data
    const long long* p = (const long long*)eidx;
    s = (int)p[i]; d = (int)p[E + i];
  }
  src32[i] = s;
  dst32[i] = d;
  atomicAdd(&counts[d], 1);
}

// ----- hierarchical exclusive scan of counts[M] -> offs, cursor ------------
// Phase A: per-block (1024 counts) reduce -> blockSums
__global__ void scanA_k(const int* __restrict__ counts,
                        int* __restrict__ blockSums, int M) {
  __shared__ int ts[256];
  int b = blockIdx.x, t = threadIdx.x;
  int base = b * 1024 + t * 4;
  int s = 0;
#pragma unroll
  for (int k = 0; k < 4; k++) { int i = base + k; if (i < M) s += counts[i]; }
  ts[t] = s;
  __syncthreads();
  for (int off = 128; off > 0; off >>= 1) {
    if (t < off) ts[t] += ts[t + off];
    __syncthreads();
  }
  if (t == 0) blockSums[b] = ts[0];
}

// Phase C: each block wave-scans blockSums (nb<=64) itself, then local scan.
__global__ void scanC_k(const int* __restrict__ counts,
                        const int* __restrict__ bsums,
                        int* __restrict__ offs, int* __restrict__ cursor,
                        int M, int E, int nb) {
  __shared__ int ts[256];
  __shared__ int bofs;
  int b = blockIdx.x, t = threadIdx.x;
  if (t < 64) {
    int v = (t < nb) ? bsums[t] : 0;
    int orig = v;
#pragma unroll
    for (int off = 1; off < 64; off <<= 1) {
      int u = __shfl_up(v, off);
      if (t >= off) v += u;
    }
    if (t == b) bofs = v - orig;   // exclusive prefix of this block
  }
  int base = b * 1024 + t * 4;
  int v[4]; int s = 0;
#pragma unroll
  for (int k = 0; k < 4; k++) {
    int i = base + k;
    v[k] = (i < M) ? counts[i] : 0;
    s += v[k];
  }
  ts[t] = s;
  __syncthreads();
  for (int off = 1; off < 256; off <<= 1) {
    int x = (t >= off) ? ts[t - off] : 0;
    __syncthreads();
    ts[t] += x;
    __syncthreads();
  }
  int run = bofs + ts[t] - s;
#pragma unroll
  for (int k = 0; k < 4; k++) {
    int i = base + k;
    if (i < M) { offs[i] = run; cursor[i] = run; run += v[k]; }
  }
  if (b == 0 && t == 0) offs[M] = E;
}

__global__ void fill_k(const int* __restrict__ src, const int* __restrict__ dst,
                       int* __restrict__ cursor, int* __restrict__ csr, int E) {
  int i = blockIdx.x * 256 + threadIdx.x;
  if (i >= E) return;
  int pos = atomicAdd(&cursor[dst[i]], 1);
  csr[pos] = src[i];
}

// --------------------------- weight conversion -----------------------------

// wb rows 0..255 = W1_l, 256..511 = W1_r  (each [256,768])
__global__ void cvtw_k(const float* __restrict__ W1l, const float* __restrict__ W1r,
                       unsigned short* __restrict__ wb) {
  int idx = blockIdx.x * 256 + threadIdx.x;   // chunk of 8
  int total = N1 * (D_IN / 8);
  if (idx >= total) return;
  int row = idx / (D_IN / 8);
  int cpos = (idx % (D_IN / 8)) * 8;
  const float* p = (row < D_HID) ? (W1l + (size_t)row * D_IN + cpos)
                                 : (W1r + (size_t)(row - D_HID) * D_IN + cpos);
  float4 f0 = *(const float4*)p;
  float4 f1 = *(const float4*)(p + 4);
  short8 o;
  o[0] = (short)f2bf(f0.x); o[1] = (short)f2bf(f0.y);
  o[2] = (short)f2bf(f0.z); o[3] = (short)f2bf(f0.w);
  o[4] = (short)f2bf(f1.x); o[5] = (short)f2bf(f1.y);
  o[6] = (short)f2bf(f1.z); o[7] = (short)f2bf(f1.w);
  *(short8*)(wb + (size_t)idx * 8) = o;
}

// --------------------------- layer-1 GEMM ----------------------------------
// Cb[Mp, 512](bf16) = bf16(x[M, 768]) @ wb[512, 768]^T
// 128x128 tile, BK=32, 4 waves, each wave 64x64 via 4x4 of 16x16x32 MFMA.
// A staged explicitly: float4 global loads -> RNE cvt -> ds_write_b128 into
// K-major segment layout (seg = row>>4, chunk (row,kg) at byte
// seg*1024 + kg*256 + (row&15)*16). B staged via global_load_lds (bf16).
// Frag reads: 16 consecutive lanes -> 256B contiguous -> conflict-free.
__global__ __launch_bounds__(256) void gemm_k(
    const float* __restrict__ x,
    const unsigned short* __restrict__ wb,
    unsigned short* __restrict__ Cb, int M) {
  __shared__ unsigned short As[128 * 32];   // 8 KB
  __shared__ unsigned short Bs[128 * 32];   // 8 KB
  const int tid  = threadIdx.x;
  const int lane = tid & 63;
  const int wid  = tid >> 6;
  const int wr = wid >> 1, wc = wid & 1;
  const int m0 = blockIdx.y * 128;   // n fastest in dispatch -> A-tile reuse
  const int n0 = blockIdx.x * 128;
  const int l15  = lane & 15;
  const int quad = lane >> 4;

  // A chunk assignments: chunk c in [0,512): row=c>>2, kg=c&3 (8 floats)
  const int ca0 = tid, ca1 = 256 + tid;
  const int arow0 = ca0 >> 2, akg0 = ca0 & 3;
  const int arow1 = ca1 >> 2, akg1 = ca1 & 3;
  const float* agp0 = x + (size_t)min(m0 + arow0, M - 1) * D_IN + akg0 * 8;
  const float* agp1 = x + (size_t)min(m0 + arow1, M - 1) * D_IN + akg1 * 8;
  unsigned short* alp0 = &As[(arow0 >> 4) * 512 + akg0 * 128 + (arow0 & 15) * 8];
  unsigned short* alp1 = &As[(arow1 >> 4) * 512 + akg1 * 128 + (arow1 & 15) * 8];

  f32x4 acc[4][4];
#pragma unroll
  for (int r = 0; r < 4; r++)
#pragma unroll
    for (int c = 0; c < 4; c++) acc[r][c] = (f32x4)0.0f;

  for (int k0 = 0; k0 < D_IN; k0 += 32) {
    __syncthreads();   // previous iteration's LDS reads done
    // A: explicit loads (issued first so their waitcnt leaves async B in flight)
    float4 a00 = *(const float4*)(agp0 + k0);
    float4 a01 = *(const float4*)(agp0 + k0 + 4);
    float4 a10 = *(const float4*)(agp1 + k0);
    float4 a11 = *(const float4*)(agp1 + k0 + 4);
    // B: async bf16 staging, K-major segments
#pragma unroll
    for (int l = 0; l < 2; ++l) {
      int cb = l * 256 + tid;
      int row = (cb >> 6) * 16 + (cb & 15);
      int cg  = (cb >> 4) & 3;
      async_copy16(wb + (size_t)(n0 + row) * D_IN + k0 + cg * 8, &Bs[cb * 8]);
    }
    // convert + LDS write A
    short8 o0, o1;
    o0[0] = (short)f2bf(a00.x); o0[1] = (short)f2bf(a00.y);
    o0[2] = (short)f2bf(a00.z); o0[3] = (short)f2bf(a00.w);
    o0[4] = (short)f2bf(a01.x); o0[5] = (short)f2bf(a01.y);
    o0[6] = (short)f2bf(a01.z); o0[7] = (short)f2bf(a01.w);
    o1[0] = (short)f2bf(a10.x); o1[1] = (short)f2bf(a10.y);
    o1[2] = (short)f2bf(a10.z); o1[3] = (short)f2bf(a10.w);
    o1[4] = (short)f2bf(a11.x); o1[5] = (short)f2bf(a11.y);
    o1[6] = (short)f2bf(a11.z); o1[7] = (short)f2bf(a11.w);
    *(short8*)alp0 = o0;
    *(short8*)alp1 = o1;
    __syncthreads();   // staging drained (A writes + async B)

    short8 a[4], b[4];
#pragma unroll
    for (int r = 0; r < 4; r++)
      a[r] = *(const short8*)&As[(wr * 4 + r) * 512 + quad * 128 + l15 * 8];
#pragma unroll
    for (int c = 0; c < 4; c++)
      b[c] = *(const short8*)&Bs[(wc * 4 + c) * 512 + quad * 128 + l15 * 8];
#pragma unroll
    for (int r = 0; r < 4; r++)
#pragma unroll
      for (int c = 0; c < 4; c++)
        acc[r][c] = __builtin_amdgcn_mfma_f32_16x16x32_bf16(a[r], b[c], acc[r][c], 0, 0, 0);
  }

  // epilogue: C/D layout col=lane&15, row=(lane>>4)*4+reg; store bf16
  const int crow0 = m0 + wr * 64;
  const int ccol0 = n0 + wc * 64;
#pragma unroll
  for (int r = 0; r < 4; r++)
#pragma unroll
    for (int c = 0; c < 4; c++) {
      int col = ccol0 + c * 16 + l15;
#pragma unroll
      for (int reg = 0; reg < 4; reg++) {
        int row = crow0 + r * 16 + quad * 4 + reg;
        Cb[(size_t)row * N1 + col] = f2bf(acc[r][c][reg]);
      }
    }
}

// --------------------- fused aggregate + epilogue + layer-2 ----------------
// h[c] = relu( mean_{j in N(i)} Cb[j][c] + b1[c] + Cb[i][256+c] )  (registers)
// rs[i] = { h@W2_l[0], h@W2_l[1], h@W2_r[0], h@W2_r[1] }
__global__ void agg_l2_k(const unsigned short* __restrict__ Cb,
                         const int* __restrict__ offs, const int* __restrict__ csr,
                         const float* __restrict__ b1,
                         const float* __restrict__ W2l, const float* __restrict__ W2r,
                         float4* __restrict__ rs, int M) {
  int tid = threadIdx.x;
  int lane = tid & 63;
  int wid = tid >> 6;
  int wave = blockIdx.x * 4 + wid;
  int nw = gridDim.x * 4;
  int c = lane * 4;
  float4 bv  = *(const float4*)(b1 + c);
  float4 wl0 = *(const float4*)(W2l + c);
  float4 wl1 = *(const float4*)(W2l + D_HID + c);
  float4 wr0 = *(const float4*)(W2r + c);
  float4 wr1 = *(const float4*)(W2r + D_HID + c);
  for (int i = wave; i < M; i += nw) {
    int s = offs[i], e = offs[i + 1];
    float ax = 0.f, ay = 0.f, az = 0.f, aw = 0.f;
    for (int t = s; t < e; t++) {
      int j = csr[t];
      ushort4 v = *(const ushort4*)(Cb + (size_t)j * N1 + c);
      ax += bf2f(v.x); ay += bf2f(v.y); az += bf2f(v.z); aw += bf2f(v.w);
    }
    float inv = 1.0f / fmaxf((float)(e - s), 1.0f);
    ushort4 q = *(const ushort4*)(Cb + (size_t)i * N1 + D_HID + c);
    float h0 = fmaxf(ax * inv + bv.x + bf2f(q.x), 0.0f);
    float h1 = fmaxf(ay * inv + bv.y + bf2f(q.y), 0.0f);
    float h2 = fmaxf(az * inv + bv.z + bf2f(q.z), 0.0f);
    float h3 = fmaxf(aw * inv + bv.w + bf2f(q.w), 0.0f);
    float r0 = h0 * wl0.x + h1 * wl0.y + h2 * wl0.z + h3 * wl0.w;
    float r1 = h0 * wl1.x + h1 * wl1.y + h2 * wl1.z + h3 * wl1.w;
    float s0 = h0 * wr0.x + h1 * wr0.y + h2 * wr0.z + h3 * wr0.w;
    float s1 = h0 * wr1.x + h1 * wr1.y + h2 * wr1.z + h3 * wr1.w;
#pragma unroll
    for (int off = 32; off > 0; off >>= 1) {
      r0 += __shfl_xor(r0, off);
      r1 += __shfl_xor(r1, off);
      s0 += __shfl_xor(s0, off);
      s1 += __shfl_xor(s1, off);
    }
    if (lane == 0) rs[i] = make_float4(r0, r1, s0, s1);
  }
}

// --------------------------- final -----------------------------------------
// out[i][j] = mean_{k in N(i)} rs[k][j] + b2[j] + rs[i][2+j]
__global__ void final_k(const float4* __restrict__ rs, const int* __restrict__ offs,
                        const int* __restrict__ csr, const float* __restrict__ b2,
                        float* __restrict__ out, int M) {
  int i = blockIdx.x * 256 + threadIdx.x;
  if (i >= M) return;
  int s = offs[i], e = offs[i + 1];
  float a0 = 0.0f, a1 = 0.0f;
  for (int t = s; t < e; t++) {
    float4 v = rs[csr[t]];
    a0 += v.x; a1 += v.y;
  }
  float inv = 1.0f / fmaxf((float)(e - s), 1.0f);
  float4 me = rs[i];
  out[2 * i + 0] = a0 * inv + b2[0] + me.z;
  out[2 * i + 1] = a1 * inv + b2[1] + me.w;
}

// ---------------------------------------------------------------------------

extern "C" void kernel_launch(void* const* d_in, const int* in_sizes, int n_in,
                              void* d_out, int out_size, void* d_ws, size_t ws_size,
                              hipStream_t stream) {
  const float* x   = (const float*)d_in[0];
  const void*  eix = d_in[1];
  const float* W1l = (const float*)d_in[2];
  const float* b1  = (const float*)d_in[3];
  const float* W1r = (const float*)d_in[4];
  const float* W2l = (const float*)d_in[5];
  const float* b2  = (const float*)d_in[6];
  const float* W2r = (const float*)d_in[7];
  float* out = (float*)d_out;

  const int M  = in_sizes[0] / D_IN;       // 50000
  const int E  = in_sizes[1] / 2;          // 250000
  const int Mp = ((M + 127) / 128) * 128;  // 50048
  const int nb = (M + 1023) / 1024;        // scan blocks (<=64)

  // workspace layout (256B aligned slots)
  char* ws = (char*)d_ws;
  size_t off = 0;
  auto alloc = [&](size_t b) { size_t o = off; off += (b + 255) & ~(size_t)255; return o; };
  size_t oFlag   = alloc(4);
  size_t oCounts = alloc((size_t)M * 4);
  size_t zeroBytes = oCounts + (size_t)M * 4;      // flag + counts
  size_t oOffs   = alloc((size_t)(M + 1) * 4);
  size_t oCursor = alloc((size_t)M * 4);
  size_t oCsr    = alloc((size_t)E * 4);
  size_t oSrc    = alloc((size_t)E * 4);
  size_t oDst    = alloc((size_t)E * 4);
  size_t oBSums  = alloc(64 * 4);
  size_t oWb     = alloc((size_t)N1 * D_IN * 2);
  size_t oC      = alloc((size_t)Mp * N1 * 2);     // bf16
  size_t oRs     = alloc((size_t)M * 16);
  (void)ws_size; (void)n_in; (void)out_size;

  unsigned int* flag = (unsigned int*)(ws + oFlag);
  int* counts = (int*)(ws + oCounts);
  int* offs   = (int*)(ws + oOffs);
  int* cursor = (int*)(ws + oCursor);
  int* csr    = (int*)(ws + oCsr);
  int* src32  = (int*)(ws + oSrc);
  int* dst32  = (int*)(ws + oDst);
  int* bsums  = (int*)(ws + oBSums);
  unsigned short* wb = (unsigned short*)(ws + oWb);
  unsigned short* Cb = (unsigned short*)(ws + oC);
  float4* rs = (float4*)(ws + oRs);

  hipMemsetAsync(ws, 0, zeroBytes, stream);

  int gE = (E + 255) / 256;
  detect_k<<<gE, 256, 0, stream>>>((const unsigned int*)eix, flag, E);
  cvtidx_k<<<gE, 256, 0, stream>>>(eix, flag, src32, dst32, counts, E);
  scanA_k<<<nb, 256, 0, stream>>>(counts, bsums, M);
  scanC_k<<<nb, 256, 0, stream>>>(counts, bsums, offs, cursor, M, E, nb);
  fill_k<<<gE, 256, 0, stream>>>(src32, dst32, cursor, csr, E);

  int gW = (N1 * (D_IN / 8) + 255) / 256;
  cvtw_k<<<gW, 256, 0, stream>>>(W1l, W1r, wb);

  dim3 gg(N1 / 128, Mp / 128);   // n fastest -> A-tile reuse across n-blocks
  gemm_k<<<gg, 256, 0, stream>>>(x, wb, Cb, M);

  agg_l2_k<<<2048, 256, 0, stream>>>(Cb, offs, csr, b1, W2l, W2r, rs, M);
  final_k<<<(M + 255) / 256, 256, 0, stream>>>(rs, offs, csr, b2, out, M);
}

// Round 5
// 388.553 us; speedup vs baseline: 1.6597x; 1.1202x over previous
//
#include <hip/hip_runtime.h>
#include <stdint.h>

// ---------------------------------------------------------------------------
// GraphSAGE 2-layer: out = SAGE2(relu(SAGE1(x)))
// SAGE(x) = mean_agg(x@W_l.T) + b + x@W_r.T   (project-then-aggregate rewrite)
// R5: gemm K-loop restructured to ONE barrier/iter with double-buffered LDS;
//     next iter's A-regs + async-B issued AFTER the barrier (fly behind MFMA).
//     A ds_writes XOR-swizzled (r15 ^ P(kg)) -> 2-way (free) on write & read,
//     while keeping 128B/phase coalesced global A loads. detect folded into
//     cvtidx (block-local ballot).
// ---------------------------------------------------------------------------

#define D_IN  768
#define D_HID 256
#define N1    512   // concat(W1_l, W1_r) output width
#define KITERS (D_IN / 32)

typedef __attribute__((ext_vector_type(8))) short short8;
typedef __attribute__((ext_vector_type(4))) float f32x4;

__device__ __forceinline__ void async_copy16(const void* g, void* l) {
  __builtin_amdgcn_global_load_lds(
      (const __attribute__((address_space(1))) unsigned int*)g,
      (__attribute__((address_space(3))) unsigned int*)l,
      16, 0, 0);
}

__device__ __forceinline__ unsigned short f2bf(float f) {
  union { float f; unsigned u; } v; v.f = f;
  unsigned r = v.u + 0x7FFFu + ((v.u >> 16) & 1u);   // RNE
  return (unsigned short)(r >> 16);
}

__device__ __forceinline__ float bf2f(unsigned short b) {
  union { unsigned u; float f; } v; v.u = ((unsigned)b) << 16;
  return v.f;
}

// --------------------------- index handling --------------------------------

// convert + count, with block-local int64/int32 detection:
// if data is int64 (LE, values < 2^31), every odd 32-bit word is 0.
__global__ void cvtidx_k(const void* __restrict__ eidx,
                         int* __restrict__ src32, int* __restrict__ dst32,
                         int* __restrict__ counts, int E) {
  __shared__ int flag32;
  int tid = threadIdx.x;
  int i = blockIdx.x * 256 + tid;
  unsigned v = (i < E) ? ((const unsigned int*)eidx)[2 * (size_t)i + 1] : 0u;
  unsigned long long any = __ballot(v != 0u);
  if (tid == 0) flag32 = 0;
  __syncthreads();
  if ((tid & 63) == 0 && any) flag32 = 1;   // benign multi-writer (same value)
  __syncthreads();
  if (i >= E) return;
  int s, d;
  if (flag32) {  // int32 data
    const int* p = (const int*)eidx;
    s = p[i]; d = p[E + i];
  } else {       // int64 data
    const long long* p = (const long long*)eidx;
    s = (int)p[i]; d = (int)p[E + i];
  }
  src32[i] = s;
  dst32[i] = d;
  atomicAdd(&counts[d], 1);
}

// ----- hierarchical exclusive scan of counts[M] -> offs, cursor ------------
__global__ void scanA_k(const int* __restrict__ counts,
                        int* __restrict__ blockSums, int M) {
  __shared__ int ts[256];
  int b = blockIdx.x, t = threadIdx.x;
  int base = b * 1024 + t * 4;
  int s = 0;
#pragma unroll
  for (int k = 0; k < 4; k++) { int i = base + k; if (i < M) s += counts[i]; }
  ts[t] = s;
  __syncthreads();
  for (int off = 128; off > 0; off >>= 1) {
    if (t < off) ts[t] += ts[t + off];
    __syncthreads();
  }
  if (t == 0) blockSums[b] = ts[0];
}

// Each block wave-scans blockSums (nb<=64) itself, then local scan.
__global__ void scanC_k(const int* __restrict__ counts,
                        const int* __restrict__ bsums,
                        int* __restrict__ offs, int* __restrict__ cursor,
                        int M, int E, int nb) {
  __shared__ int ts[256];
  __shared__ int bofs;
  int b = blockIdx.x, t = threadIdx.x;
  if (t < 64) {
    int v = (t < nb) ? bsums[t] : 0;
    int orig = v;
#pragma unroll
    for (int off = 1; off < 64; off <<= 1) {
      int u = __shfl_up(v, off);
      if (t >= off) v += u;
    }
    if (t == b) bofs = v - orig;   // exclusive prefix of this block
  }
  int base = b * 1024 + t * 4;
  int v[4]; int s = 0;
#pragma unroll
  for (int k = 0; k < 4; k++) {
    int i = base + k;
    v[k] = (i < M) ? counts[i] : 0;
    s += v[k];
  }
  ts[t] = s;
  __syncthreads();
  for (int off = 1; off < 256; off <<= 1) {
    int x = (t >= off) ? ts[t - off] : 0;
    __syncthreads();
    ts[t] += x;
    __syncthreads();
  }
  int run = bofs + ts[t] - s;
#pragma unroll
  for (int k = 0; k < 4; k++) {
    int i = base + k;
    if (i < M) { offs[i] = run; cursor[i] = run; run += v[k]; }
  }
  if (b == 0 && t == 0) offs[M] = E;
}

__global__ void fill_k(const int* __restrict__ src, const int* __restrict__ dst,
                       int* __restrict__ cursor, int* __restrict__ csr, int E) {
  int i = blockIdx.x * 256 + threadIdx.x;
  if (i >= E) return;
  int pos = atomicAdd(&cursor[dst[i]], 1);
  csr[pos] = src[i];
}

// --------------------------- weight conversion -----------------------------

// wb rows 0..255 = W1_l, 256..511 = W1_r  (each [256,768])
__global__ void cvtw_k(const float* __restrict__ W1l, const float* __restrict__ W1r,
                       unsigned short* __restrict__ wb) {
  int idx = blockIdx.x * 256 + threadIdx.x;   // chunk of 8
  int total = N1 * (D_IN / 8);
  if (idx >= total) return;
  int row = idx / (D_IN / 8);
  int cpos = (idx % (D_IN / 8)) * 8;
  const float* p = (row < D_HID) ? (W1l + (size_t)row * D_IN + cpos)
                                 : (W1r + (size_t)(row - D_HID) * D_IN + cpos);
  float4 f0 = *(const float4*)p;
  float4 f1 = *(const float4*)(p + 4);
  short8 o;
  o[0] = (short)f2bf(f0.x); o[1] = (short)f2bf(f0.y);
  o[2] = (short)f2bf(f0.z); o[3] = (short)f2bf(f0.w);
  o[4] = (short)f2bf(f1.x); o[5] = (short)f2bf(f1.y);
  o[6] = (short)f2bf(f1.z); o[7] = (short)f2bf(f1.w);
  *(short8*)(wb + (size_t)idx * 8) = o;
}

// --------------------------- layer-1 GEMM ----------------------------------
// Cb[Mp, 512](bf16) = bf16(x[M, 768]) @ wb[512, 768]^T
// 128x128 tile, BK=32, 4 waves, wave 64x64 via 4x4 of 16x16x32 MFMA.
// One barrier per K-iter, double-buffered LDS; next iter's staging issued
// after the barrier so it overlaps MFMA. A ds_writes XOR-swizzled.
__global__ __launch_bounds__(256) void gemm_k(
    const float* __restrict__ x,
    const unsigned short* __restrict__ wb,
    unsigned short* __restrict__ Cb, int M) {
  __shared__ unsigned short As[2][128 * 32];   // 16 KB
  __shared__ unsigned short Bs[2][128 * 32];   // 16 KB
  const int tid  = threadIdx.x;
  const int lane = tid & 63;
  const int wid  = tid >> 6;
  const int wr = wid >> 1, wc = wid & 1;
  const int m0 = blockIdx.y * 128;   // n fastest in dispatch -> A-tile L3 reuse
  const int n0 = blockIdx.x * 128;
  const int l15  = lane & 15;
  const int quad = lane >> 4;

  // A chunks: c0=tid, c1=tid+256; row=c>>2, kg=c&3 (coalesced 128B per phase)
  const int arow0 = tid >> 2, akg = tid & 3;
  const int arow1 = arow0 + 64;
  const int aswz = akg | ((akg & 1) << 2);          // P(kg) in {0,5,2,7}
  const float* agp0 = x + (size_t)min(m0 + arow0, M - 1) * D_IN + akg * 8;
  const float* agp1 = x + (size_t)min(m0 + arow1, M - 1) * D_IN + akg * 8;
  const int aoff0 = (arow0 >> 4) * 512 + akg * 128 + ((arow0 & 15) ^ aswz) * 8;
  const int aoff1 = (arow1 >> 4) * 512 + akg * 128 + ((arow1 & 15) ^ aswz) * 8;
  const int pquad = quad | ((quad & 1) << 2);       // P(quad) for frag reads

  // B chunks: cb0=tid, cb1=tid+256; K-major segments (async -> conflict-free)
  const int brow = (tid >> 6) * 16 + (tid & 15);
  const int bcg  = (tid >> 4) & 3;
  const unsigned short* bgp0 = wb + (size_t)(n0 + brow) * D_IN + bcg * 8;
  const unsigned short* bgp1 = wb + (size_t)(n0 + brow + 64) * D_IN + bcg * 8;
  const int boff0 = tid * 8;
  const int boff1 = (tid + 256) * 8;

  f32x4 acc[4][4];
#pragma unroll
  for (int r = 0; r < 4; r++)
#pragma unroll
    for (int c = 0; c < 4; c++) acc[r][c] = (f32x4)0.0f;

  // prologue: stage iter 0
  float4 a00 = *(const float4*)(agp0);
  float4 a01 = *(const float4*)(agp0 + 4);
  float4 a10 = *(const float4*)(agp1);
  float4 a11 = *(const float4*)(agp1 + 4);
  async_copy16(bgp0, &Bs[0][boff0]);
  async_copy16(bgp1, &Bs[0][boff1]);

  for (int it = 0; it < KITERS; ++it) {
    const int p = it & 1;
    // convert + LDS write A(it)  (a-regs loaded one iter ago)
    short8 o0, o1;
    o0[0] = (short)f2bf(a00.x); o0[1] = (short)f2bf(a00.y);
    o0[2] = (short)f2bf(a00.z); o0[3] = (short)f2bf(a00.w);
    o0[4] = (short)f2bf(a01.x); o0[5] = (short)f2bf(a01.y);
    o0[6] = (short)f2bf(a01.z); o0[7] = (short)f2bf(a01.w);
    o1[0] = (short)f2bf(a10.x); o1[1] = (short)f2bf(a10.y);
    o1[2] = (short)f2bf(a10.z); o1[3] = (short)f2bf(a10.w);
    o1[4] = (short)f2bf(a11.x); o1[5] = (short)f2bf(a11.y);
    o1[6] = (short)f2bf(a11.z); o1[7] = (short)f2bf(a11.w);
    *(short8*)&As[p][aoff0] = o0;
    *(short8*)&As[p][aoff1] = o1;

    __syncthreads();   // drains: A-writes (lgkm) + async B(it) issued LAST iter
                       // (mostly arrived -> cheap), makes As[p]/Bs[p] visible

    if (it + 1 < KITERS) {
      const int k1 = (it + 1) * 32;
      // next A into regs, next B async -> both overlap the MFMA block below
      a00 = *(const float4*)(agp0 + k1);
      a01 = *(const float4*)(agp0 + k1 + 4);
      a10 = *(const float4*)(agp1 + k1);
      a11 = *(const float4*)(agp1 + k1 + 4);
      async_copy16(bgp0 + k1, &Bs[p ^ 1][boff0]);
      async_copy16(bgp1 + k1, &Bs[p ^ 1][boff1]);
    }

    short8 a[4], b[4];
#pragma unroll
    for (int r = 0; r < 4; r++)
      a[r] = *(const short8*)&As[p][(wr * 4 + r) * 512 + quad * 128 + ((l15 ^ pquad)) * 8];
#pragma unroll
    for (int c = 0; c < 4; c++)
      b[c] = *(const short8*)&Bs[p][(wc * 4 + c) * 512 + quad * 128 + l15 * 8];
#pragma unroll
    for (int r = 0; r < 4; r++)
#pragma unroll
      for (int c = 0; c < 4; c++)
        acc[r][c] = __builtin_amdgcn_mfma_f32_16x16x32_bf16(a[r], b[c], acc[r][c], 0, 0, 0);
  }

  // epilogue: C/D layout col=lane&15, row=(lane>>4)*4+reg; store bf16
  const int crow0 = m0 + wr * 64;
  const int ccol0 = n0 + wc * 64;
#pragma unroll
  for (int r = 0; r < 4; r++)
#pragma unroll
    for (int c = 0; c < 4; c++) {
      int col = ccol0 + c * 16 + l15;
#pragma unroll
      for (int reg = 0; reg < 4; reg++) {
        int row = crow0 + r * 16 + quad * 4 + reg;
        Cb[(size_t)row * N1 + col] = f2bf(acc[r][c][reg]);
      }
    }
}

// --------------------- fused aggregate + epilogue + layer-2 ----------------
// h[c] = relu( mean_{j in N(i)} Cb[j][c] + b1[c] + Cb[i][256+c] )  (registers)
// rs[i] = { h@W2_l[0], h@W2_l[1], h@W2_r[0], h@W2_r[1] }
__global__ void agg_l2_k(const unsigned short* __restrict__ Cb,
                         const int* __restrict__ offs, const int* __restrict__ csr,
                         const float* __restrict__ b1,
                         const float* __restrict__ W2l, const float* __restrict__ W2r,
                         float4* __restrict__ rs, int M) {
  int tid = threadIdx.x;
  int lane = tid & 63;
  int wid = tid >> 6;
  int wave = blockIdx.x * 4 + wid;
  int nw = gridDim.x * 4;
  int c = lane * 4;
  float4 bv  = *(const float4*)(b1 + c);
  float4 wl0 = *(const float4*)(W2l + c);
  float4 wl1 = *(const float4*)(W2l + D_HID + c);
  float4 wr0 = *(const float4*)(W2r + c);
  float4 wr1 = *(const float4*)(W2r + D_HID + c);
  for (int i = wave; i < M; i += nw) {
    int s = offs[i], e = offs[i + 1];
    float ax = 0.f, ay = 0.f, az = 0.f, aw = 0.f;
    for (int t = s; t < e; t++) {
      int j = csr[t];
      ushort4 v = *(const ushort4*)(Cb + (size_t)j * N1 + c);
      ax += bf2f(v.x); ay += bf2f(v.y); az += bf2f(v.z); aw += bf2f(v.w);
    }
    float inv = 1.0f / fmaxf((float)(e - s), 1.0f);
    ushort4 q = *(const ushort4*)(Cb + (size_t)i * N1 + D_HID + c);
    float h0 = fmaxf(ax * inv + bv.x + bf2f(q.x), 0.0f);
    float h1 = fmaxf(ay * inv + bv.y + bf2f(q.y), 0.0f);
    float h2 = fmaxf(az * inv + bv.z + bf2f(q.z), 0.0f);
    float h3 = fmaxf(aw * inv + bv.w + bf2f(q.w), 0.0f);
    float r0 = h0 * wl0.x + h1 * wl0.y + h2 * wl0.z + h3 * wl0.w;
    float r1 = h0 * wl1.x + h1 * wl1.y + h2 * wl1.z + h3 * wl1.w;
    float s0 = h0 * wr0.x + h1 * wr0.y + h2 * wr0.z + h3 * wr0.w;
    float s1 = h0 * wr1.x + h1 * wr1.y + h2 * wr1.z + h3 * wr1.w;
#pragma unroll
    for (int off = 32; off > 0; off >>= 1) {
      r0 += __shfl_xor(r0, off);
      r1 += __shfl_xor(r1, off);
      s0 += __shfl_xor(s0, off);
      s1 += __shfl_xor(s1, off);
    }
    if (lane == 0) rs[i] = make_float4(r0, r1, s0, s1);
  }
}

// --------------------------- final -----------------------------------------
// out[i][j] = mean_{k in N(i)} rs[k][j] + b2[j] + rs[i][2+j]
__global__ void final_k(const float4* __restrict__ rs, const int* __restrict__ offs,
                        const int* __restrict__ csr, const float* __restrict__ b2,
                        float* __restrict__ out, int M) {
  int i = blockIdx.x * 256 + threadIdx.x;
  if (i >= M) return;
  int s = offs[i], e = offs[i + 1];
  float a0 = 0.0f, a1 = 0.0f;
  for (int t = s; t < e; t++) {
    float4 v = rs[csr[t]];
    a0 += v.x; a1 += v.y;
  }
  float inv = 1.0f / fmaxf((float)(e - s), 1.0f);
  float4 me = rs[i];
  out[2 * i + 0] = a0 * inv + b2[0] + me.z;
  out[2 * i + 1] = a1 * inv + b2[1] + me.w;
}

// ---------------------------------------------------------------------------

extern "C" void kernel_launch(void* const* d_in, const int* in_sizes, int n_in,
                              void* d_out, int out_size, void* d_ws, size_t ws_size,
                              hipStream_t stream) {
  const float* x   = (const float*)d_in[0];
  const void*  eix = d_in[1];
  const float* W1l = (const float*)d_in[2];
  const float* b1  = (const float*)d_in[3];
  const float* W1r = (const float*)d_in[4];
  const float* W2l = (const float*)d_in[5];
  const float* b2  = (const float*)d_in[6];
  const float* W2r = (const float*)d_in[7];
  float* out = (float*)d_out;

  const int M  = in_sizes[0] / D_IN;       // 50000
  const int E  = in_sizes[1] / 2;          // 250000
  const int Mp = ((M + 127) / 128) * 128;  // 50048
  const int nb = (M + 1023) / 1024;        // scan blocks (<=64)

  // workspace layout (256B aligned slots)
  char* ws = (char*)d_ws;
  size_t off = 0;
  auto alloc = [&](size_t b) { size_t o = off; off += (b + 255) & ~(size_t)255; return o; };
  size_t oCounts = alloc((size_t)M * 4);
  size_t zeroBytes = (size_t)M * 4;        // counts
  size_t oOffs   = alloc((size_t)(M + 1) * 4);
  size_t oCursor = alloc((size_t)M * 4);
  size_t oCsr    = alloc((size_t)E * 4);
  size_t oSrc    = alloc((size_t)E * 4);
  size_t oDst    = alloc((size_t)E * 4);
  size_t oBSums  = alloc(64 * 4);
  size_t oWb     = alloc((size_t)N1 * D_IN * 2);
  size_t oC      = alloc((size_t)Mp * N1 * 2);     // bf16
  size_t oRs     = alloc((size_t)M * 16);
  (void)ws_size; (void)n_in; (void)out_size;

  int* counts = (int*)(ws + oCounts);
  int* offs   = (int*)(ws + oOffs);
  int* cursor = (int*)(ws + oCursor);
  int* csr    = (int*)(ws + oCsr);
  int* src32  = (int*)(ws + oSrc);
  int* dst32  = (int*)(ws + oDst);
  int* bsums  = (int*)(ws + oBSums);
  unsigned short* wb = (unsigned short*)(ws + oWb);
  unsigned short* Cb = (unsigned short*)(ws + oC);
  float4* rs = (float4*)(ws + oRs);

  hipMemsetAsync(counts, 0, zeroBytes, stream);

  int gE = (E + 255) / 256;
  cvtidx_k<<<gE, 256, 0, stream>>>(eix, src32, dst32, counts, E);
  scanA_k<<<nb, 256, 0, stream>>>(counts, bsums, M);
  scanC_k<<<nb, 256, 0, stream>>>(counts, bsums, offs, cursor, M, E, nb);
  fill_k<<<gE, 256, 0, stream>>>(src32, dst32, cursor, csr, E);

  int gW = (N1 * (D_IN / 8) + 255) / 256;
  cvtw_k<<<gW, 256, 0, stream>>>(W1l, W1r, wb);

  dim3 gg(N1 / 128, Mp / 128);   // n fastest -> A-tile reuse across n-blocks
  gemm_k<<<gg, 256, 0, stream>>>(x, wb, Cb, M);

  agg_l2_k<<<2048, 256, 0, stream>>>(Cb, offs, csr, b1, W2l, W2r, rs, M);
  final_k<<<(M + 255) / 256, 256, 0, stream>>>(rs, offs, csr, b2, out, M);
}

// Round 6
// 377.796 us; speedup vs baseline: 1.7069x; 1.0285x over previous
//
#include <hip/hip_runtime.h>
#include <stdint.h>

// ---------------------------------------------------------------------------
// GraphSAGE 2-layer: out = SAGE2(relu(SAGE1(x)))
// SAGE(x) = mean_agg(x@W_l.T) + b + x@W_r.T   (project-then-aggregate rewrite)
// R6: XCD-aware block mapping (4 n-blocks of an m-tile co-located on one XCD
//     -> A-tile L2 reuse), A register prefetch distance 2 (K-loop unrolled x2,
//     no dynamic reg indexing), one-node-per-wave agg_l2.
// ---------------------------------------------------------------------------

#define D_IN  768
#define D_HID 256
#define N1    512   // concat(W1_l, W1_r) output width
#define KITERS (D_IN / 32)

typedef __attribute__((ext_vector_type(8))) short short8;
typedef __attribute__((ext_vector_type(4))) float f32x4;

__device__ __forceinline__ void async_copy16(const void* g, void* l) {
  __builtin_amdgcn_global_load_lds(
      (const __attribute__((address_space(1))) unsigned int*)g,
      (__attribute__((address_space(3))) unsigned int*)l,
      16, 0, 0);
}

__device__ __forceinline__ unsigned short f2bf(float f) {
  union { float f; unsigned u; } v; v.f = f;
  unsigned r = v.u + 0x7FFFu + ((v.u >> 16) & 1u);   // RNE
  return (unsigned short)(r >> 16);
}

__device__ __forceinline__ float bf2f(unsigned short b) {
  union { unsigned u; float f; } v; v.u = ((unsigned)b) << 16;
  return v.f;
}

// --------------------------- index handling --------------------------------

// convert + count, with block-local int64/int32 detection:
// if data is int64 (LE, values < 2^31), every odd 32-bit word is 0.
__global__ void cvtidx_k(const void* __restrict__ eidx,
                         int* __restrict__ src32, int* __restrict__ dst32,
                         int* __restrict__ counts, int E) {
  __shared__ int flag32;
  int tid = threadIdx.x;
  int i = blockIdx.x * 256 + tid;
  unsigned v = (i < E) ? ((const unsigned int*)eidx)[2 * (size_t)i + 1] : 0u;
  unsigned long long any = __ballot(v != 0u);
  if (tid == 0) flag32 = 0;
  __syncthreads();
  if ((tid & 63) == 0 && any) flag32 = 1;   // benign multi-writer (same value)
  __syncthreads();
  if (i >= E) return;
  int s, d;
  if (flag32) {  // int32 data
    const int* p = (const int*)eidx;
    s = p[i]; d = p[E + i];
  } else {       // int64 data
    const long long* p = (const long long*)eidx;
    s = (int)p[i]; d = (int)p[E + i];
  }
  src32[i] = s;
  dst32[i] = d;
  atomicAdd(&counts[d], 1);
}

// ----- hierarchical exclusive scan of counts[M] -> offs, cursor ------------
__global__ void scanA_k(const int* __restrict__ counts,
                        int* __restrict__ blockSums, int M) {
  __shared__ int ts[256];
  int b = blockIdx.x, t = threadIdx.x;
  int base = b * 1024 + t * 4;
  int s = 0;
#pragma unroll
  for (int k = 0; k < 4; k++) { int i = base + k; if (i < M) s += counts[i]; }
  ts[t] = s;
  __syncthreads();
  for (int off = 128; off > 0; off >>= 1) {
    if (t < off) ts[t] += ts[t + off];
    __syncthreads();
  }
  if (t == 0) blockSums[b] = ts[0];
}

// Each block wave-scans blockSums (nb<=64) itself, then local scan.
__global__ void scanC_k(const int* __restrict__ counts,
                        const int* __restrict__ bsums,
                        int* __restrict__ offs, int* __restrict__ cursor,
                        int M, int E, int nb) {
  __shared__ int ts[256];
  __shared__ int bofs;
  int b = blockIdx.x, t = threadIdx.x;
  if (t < 64) {
    int v = (t < nb) ? bsums[t] : 0;
    int orig = v;
#pragma unroll
    for (int off = 1; off < 64; off <<= 1) {
      int u = __shfl_up(v, off);
      if (t >= off) v += u;
    }
    if (t == b) bofs = v - orig;   // exclusive prefix of this block
  }
  int base = b * 1024 + t * 4;
  int v[4]; int s = 0;
#pragma unroll
  for (int k = 0; k < 4; k++) {
    int i = base + k;
    v[k] = (i < M) ? counts[i] : 0;
    s += v[k];
  }
  ts[t] = s;
  __syncthreads();
  for (int off = 1; off < 256; off <<= 1) {
    int x = (t >= off) ? ts[t - off] : 0;
    __syncthreads();
    ts[t] += x;
    __syncthreads();
  }
  int run = bofs + ts[t] - s;
#pragma unroll
  for (int k = 0; k < 4; k++) {
    int i = base + k;
    if (i < M) { offs[i] = run; cursor[i] = run; run += v[k]; }
  }
  if (b == 0 && t == 0) offs[M] = E;
}

__global__ void fill_k(const int* __restrict__ src, const int* __restrict__ dst,
                       int* __restrict__ cursor, int* __restrict__ csr, int E) {
  int i = blockIdx.x * 256 + threadIdx.x;
  if (i >= E) return;
  int pos = atomicAdd(&cursor[dst[i]], 1);
  csr[pos] = src[i];
}

// --------------------------- weight conversion -----------------------------

// wb rows 0..255 = W1_l, 256..511 = W1_r  (each [256,768])
__global__ void cvtw_k(const float* __restrict__ W1l, const float* __restrict__ W1r,
                       unsigned short* __restrict__ wb) {
  int idx = blockIdx.x * 256 + threadIdx.x;   // chunk of 8
  int total = N1 * (D_IN / 8);
  if (idx >= total) return;
  int row = idx / (D_IN / 8);
  int cpos = (idx % (D_IN / 8)) * 8;
  const float* p = (row < D_HID) ? (W1l + (size_t)row * D_IN + cpos)
                                 : (W1r + (size_t)(row - D_HID) * D_IN + cpos);
  float4 f0 = *(const float4*)p;
  float4 f1 = *(const float4*)(p + 4);
  short8 o;
  o[0] = (short)f2bf(f0.x); o[1] = (short)f2bf(f0.y);
  o[2] = (short)f2bf(f0.z); o[3] = (short)f2bf(f0.w);
  o[4] = (short)f2bf(f1.x); o[5] = (short)f2bf(f1.y);
  o[6] = (short)f2bf(f1.z); o[7] = (short)f2bf(f1.w);
  *(short8*)(wb + (size_t)idx * 8) = o;
}

// --------------------------- layer-1 GEMM ----------------------------------
// Cb[Mp, 512](bf16) = bf16(x[M, 768]) @ wb[512, 768]^T
// 128x128 tile, BK=32, 4 waves, wave 64x64 via 4x4 of 16x16x32 MFMA.
// One barrier per K-iter, dbuf LDS, K-loop unrolled x2:
//   iter k: cvt+ds_write A(k) | barrier | asyncB(k+1), load A(k+2) regs | MFMA(k)
// XCD-aware bid mapping: xcd = bid&7 owns a contiguous m-tile range; the 4
// n-blocks of an m-tile are adjacent on that XCD -> A-tile L2 reuse.
__global__ __launch_bounds__(256) void gemm_k(
    const float* __restrict__ x,
    const unsigned short* __restrict__ wb,
    unsigned short* __restrict__ Cb, int M, int MT, int mtPerXcd) {
  __shared__ unsigned short As[2][128 * 32];   // 16 KB
  __shared__ unsigned short Bs[2][128 * 32];   // 16 KB

  const int bid = blockIdx.x;
  const int xcd = bid & 7;
  const int j   = bid >> 3;
  const int mt  = xcd * mtPerXcd + (j >> 2);
  if (mt >= MT) return;
  const int m0 = mt * 128;
  const int n0 = (j & 3) * 128;

  const int tid  = threadIdx.x;
  const int lane = tid & 63;
  const int wid  = tid >> 6;
  const int wr = wid >> 1, wc = wid & 1;
  const int l15  = lane & 15;
  const int quad = lane >> 4;

  // A chunks: c0=tid, c1=tid+256; row=c>>2, kg=c&3 (coalesced 128B per phase)
  const int arow0 = tid >> 2, akg = tid & 3;
  const int arow1 = arow0 + 64;
  const int aswz = akg | ((akg & 1) << 2);          // P(kg) in {0,5,2,7}
  const float* agp0 = x + (size_t)min(m0 + arow0, M - 1) * D_IN + akg * 8;
  const float* agp1 = x + (size_t)min(m0 + arow1, M - 1) * D_IN + akg * 8;
  const int aoff0 = (arow0 >> 4) * 512 + akg * 128 + ((arow0 & 15) ^ aswz) * 8;
  const int aoff1 = (arow1 >> 4) * 512 + akg * 128 + ((arow1 & 15) ^ aswz) * 8;
  const int pquad = quad | ((quad & 1) << 2);       // P(quad) for frag reads

  // B chunks: K-major segments (async -> conflict-free)
  const int brow = (tid >> 6) * 16 + (tid & 15);
  const int bcg  = (tid >> 4) & 3;
  const unsigned short* bgp0 = wb + (size_t)(n0 + brow) * D_IN + bcg * 8;
  const unsigned short* bgp1 = wb + (size_t)(n0 + brow + 64) * D_IN + bcg * 8;
  const int boff0 = tid * 8;
  const int boff1 = (tid + 256) * 8;

  f32x4 acc[4][4];
#pragma unroll
  for (int r = 0; r < 4; r++)
#pragma unroll
    for (int c = 0; c < 4; c++) acc[r][c] = (f32x4)0.0f;

  // A register staging, two sets (prefetch distance 2)
  float4 a0_0, a0_1, a0_2, a0_3;   // set 0: rows (arow0, arow1), even k-iters
  float4 a1_0, a1_1, a1_2, a1_3;   // set 1: odd k-iters

  // prologue: A(0)->set0, A(1)->set1, asyncB(0)->Bs[0]
  a0_0 = *(const float4*)(agp0);
  a0_1 = *(const float4*)(agp0 + 4);
  a0_2 = *(const float4*)(agp1);
  a0_3 = *(const float4*)(agp1 + 4);
  async_copy16(bgp0, &Bs[0][boff0]);
  async_copy16(bgp1, &Bs[0][boff1]);
  a1_0 = *(const float4*)(agp0 + 32);
  a1_1 = *(const float4*)(agp0 + 36);
  a1_2 = *(const float4*)(agp1 + 32);
  a1_3 = *(const float4*)(agp1 + 36);

#define GEMM_BODY(P, AR0, AR1, AR2, AR3)                                      \
  {                                                                           \
    short8 o0, o1;                                                            \
    o0[0] = (short)f2bf(AR0.x); o0[1] = (short)f2bf(AR0.y);                   \
    o0[2] = (short)f2bf(AR0.z); o0[3] = (short)f2bf(AR0.w);                   \
    o0[4] = (short)f2bf(AR1.x); o0[5] = (short)f2bf(AR1.y);                   \
    o0[6] = (short)f2bf(AR1.z); o0[7] = (short)f2bf(AR1.w);                   \
    o1[0] = (short)f2bf(AR2.x); o1[1] = (short)f2bf(AR2.y);                   \
    o1[2] = (short)f2bf(AR2.z); o1[3] = (short)f2bf(AR2.w);                   \
    o1[4] = (short)f2bf(AR3.x); o1[5] = (short)f2bf(AR3.y);                   \
    o1[6] = (short)f2bf(AR3.z); o1[7] = (short)f2bf(AR3.w);                   \
    *(short8*)&As[P][aoff0] = o0;                                             \
    *(short8*)&As[P][aoff1] = o1;                                             \
    __syncthreads();                                                          \
    if (kk + 1 < KITERS) {                                                    \
      const int kn = (kk + 1) * 32;                                           \
      async_copy16(bgp0 + kn, &Bs[P ^ 1][boff0]);                             \
      async_copy16(bgp1 + kn, &Bs[P ^ 1][boff1]);                             \
    }                                                                         \
    if (kk + 2 < KITERS) {                                                    \
      const int kp = (kk + 2) * 32;                                           \
      AR0 = *(const float4*)(agp0 + kp);                                      \
      AR1 = *(const float4*)(agp0 + kp + 4);                                  \
      AR2 = *(const float4*)(agp1 + kp);                                      \
      AR3 = *(const float4*)(agp1 + kp + 4);                                  \
    }                                                                         \
    short8 a[4], b[4];                                                        \
    _Pragma("unroll")                                                         \
    for (int r = 0; r < 4; r++)                                               \
      a[r] = *(const short8*)&As[P][(wr * 4 + r) * 512 + quad * 128 +         \
                                    ((l15 ^ pquad)) * 8];                     \
    _Pragma("unroll")                                                         \
    for (int c = 0; c < 4; c++)                                               \
      b[c] = *(const short8*)&Bs[P][(wc * 4 + c) * 512 + quad * 128 +         \
                                    l15 * 8];                                 \
    _Pragma("unroll")                                                         \
    for (int r = 0; r < 4; r++)                                               \
      _Pragma("unroll")                                                       \
      for (int c = 0; c < 4; c++)                                             \
        acc[r][c] =                                                           \
            __builtin_amdgcn_mfma_f32_16x16x32_bf16(a[r], b[c], acc[r][c],    \
                                                    0, 0, 0);                 \
  }

  for (int it = 0; it < KITERS; it += 2) {
    { const int kk = it;     GEMM_BODY(0, a0_0, a0_1, a0_2, a0_3) }
    { const int kk = it + 1; GEMM_BODY(1, a1_0, a1_1, a1_2, a1_3) }
  }
#undef GEMM_BODY

  // epilogue: C/D layout col=lane&15, row=(lane>>4)*4+reg; store bf16
  const int crow0 = m0 + wr * 64;
  const int ccol0 = n0 + wc * 64;
#pragma unroll
  for (int r = 0; r < 4; r++)
#pragma unroll
    for (int c = 0; c < 4; c++) {
      int col = ccol0 + c * 16 + l15;
#pragma unroll
      for (int reg = 0; reg < 4; reg++) {
        int row = crow0 + r * 16 + quad * 4 + reg;
        Cb[(size_t)row * N1 + col] = f2bf(acc[r][c][reg]);
      }
    }
}

// --------------------- fused aggregate + epilogue + layer-2 ----------------
// h[c] = relu( mean_{j in N(i)} Cb[j][c] + b1[c] + Cb[i][256+c] )  (registers)
// rs[i] = { h@W2_l[0], h@W2_l[1], h@W2_r[0], h@W2_r[1] }
// one wave per node (max TLP for the latency-bound gather)
__global__ void agg_l2_k(const unsigned short* __restrict__ Cb,
                         const int* __restrict__ offs, const int* __restrict__ csr,
                         const float* __restrict__ b1,
                         const float* __restrict__ W2l, const float* __restrict__ W2r,
                         float4* __restrict__ rs, int M) {
  int tid = threadIdx.x;
  int lane = tid & 63;
  int wid = tid >> 6;
  int i = blockIdx.x * 4 + wid;
  if (i >= M) return;
  int c = lane * 4;
  float4 bv  = *(const float4*)(b1 + c);
  float4 wl0 = *(const float4*)(W2l + c);
  float4 wl1 = *(const float4*)(W2l + D_HID + c);
  float4 wr0 = *(const float4*)(W2r + c);
  float4 wr1 = *(const float4*)(W2r + D_HID + c);
  int s = offs[i], e = offs[i + 1];
  float ax = 0.f, ay = 0.f, az = 0.f, aw = 0.f;
  for (int t = s; t < e; t++) {
    int j = csr[t];
    ushort4 v = *(const ushort4*)(Cb + (size_t)j * N1 + c);
    ax += bf2f(v.x); ay += bf2f(v.y); az += bf2f(v.z); aw += bf2f(v.w);
  }
  float inv = 1.0f / fmaxf((float)(e - s), 1.0f);
  ushort4 q = *(const ushort4*)(Cb + (size_t)i * N1 + D_HID + c);
  float h0 = fmaxf(ax * inv + bv.x + bf2f(q.x), 0.0f);
  float h1 = fmaxf(ay * inv + bv.y + bf2f(q.y), 0.0f);
  float h2 = fmaxf(az * inv + bv.z + bf2f(q.z), 0.0f);
  float h3 = fmaxf(aw * inv + bv.w + bf2f(q.w), 0.0f);
  float r0 = h0 * wl0.x + h1 * wl0.y + h2 * wl0.z + h3 * wl0.w;
  float r1 = h0 * wl1.x + h1 * wl1.y + h2 * wl1.z + h3 * wl1.w;
  float s0 = h0 * wr0.x + h1 * wr0.y + h2 * wr0.z + h3 * wr0.w;
  float s1 = h0 * wr1.x + h1 * wr1.y + h2 * wr1.z + h3 * wr1.w;
#pragma unroll
  for (int off = 32; off > 0; off >>= 1) {
    r0 += __shfl_xor(r0, off);
    r1 += __shfl_xor(r1, off);
    s0 += __shfl_xor(s0, off);
    s1 += __shfl_xor(s1, off);
  }
  if (lane == 0) rs[i] = make_float4(r0, r1, s0, s1);
}

// --------------------------- final -----------------------------------------
// out[i][j] = mean_{k in N(i)} rs[k][j] + b2[j] + rs[i][2+j]
__global__ void final_k(const float4* __restrict__ rs, const int* __restrict__ offs,
                        const int* __restrict__ csr, const float* __restrict__ b2,
                        float* __restrict__ out, int M) {
  int i = blockIdx.x * 256 + threadIdx.x;
  if (i >= M) return;
  int s = offs[i], e = offs[i + 1];
  float a0 = 0.0f, a1 = 0.0f;
  for (int t = s; t < e; t++) {
    float4 v = rs[csr[t]];
    a0 += v.x; a1 += v.y;
  }
  float inv = 1.0f / fmaxf((float)(e - s), 1.0f);
  float4 me = rs[i];
  out[2 * i + 0] = a0 * inv + b2[0] + me.z;
  out[2 * i + 1] = a1 * inv + b2[1] + me.w;
}

// ---------------------------------------------------------------------------

extern "C" void kernel_launch(void* const* d_in, const int* in_sizes, int n_in,
                              void* d_out, int out_size, void* d_ws, size_t ws_size,
                              hipStream_t stream) {
  const float* x   = (const float*)d_in[0];
  const void*  eix = d_in[1];
  const float* W1l = (const float*)d_in[2];
  const float* b1  = (const float*)d_in[3];
  const float* W1r = (const float*)d_in[4];
  const float* W2l = (const float*)d_in[5];
  const float* b2  = (const float*)d_in[6];
  const float* W2r = (const float*)d_in[7];
  float* out = (float*)d_out;

  const int M  = in_sizes[0] / D_IN;       // 50000
  const int E  = in_sizes[1] / 2;          // 250000
  const int Mp = ((M + 127) / 128) * 128;  // 50048
  const int nb = (M + 1023) / 1024;        // scan blocks (<=64)
  const int MT = Mp / 128;                 // 391 m-tiles
  const int mtPerXcd = (MT + 7) / 8;       // 49
  const int gemmBlocks = 8 * mtPerXcd * 4; // 1568 (some return early)

  // workspace layout (256B aligned slots)
  char* ws = (char*)d_ws;
  size_t off = 0;
  auto alloc = [&](size_t b) { size_t o = off; off += (b + 255) & ~(size_t)255; return o; };
  size_t oCounts = alloc((size_t)M * 4);
  size_t zeroBytes = (size_t)M * 4;        // counts
  size_t oOffs   = alloc((size_t)(M + 1) * 4);
  size_t oCursor = alloc((size_t)M * 4);
  size_t oCsr    = alloc((size_t)E * 4);
  size_t oSrc    = alloc((size_t)E * 4);
  size_t oDst    = alloc((size_t)E * 4);
  size_t oBSums  = alloc(64 * 4);
  size_t oWb     = alloc((size_t)N1 * D_IN * 2);
  size_t oC      = alloc((size_t)Mp * N1 * 2);     // bf16
  size_t oRs     = alloc((size_t)M * 16);
  (void)ws_size; (void)n_in; (void)out_size;

  int* counts = (int*)(ws + oCounts);
  int* offs   = (int*)(ws + oOffs);
  int* cursor = (int*)(ws + oCursor);
  int* csr    = (int*)(ws + oCsr);
  int* src32  = (int*)(ws + oSrc);
  int* dst32  = (int*)(ws + oDst);
  int* bsums  = (int*)(ws + oBSums);
  unsigned short* wb = (unsigned short*)(ws + oWb);
  unsigned short* Cb = (unsigned short*)(ws + oC);
  float4* rs = (float4*)(ws + oRs);

  hipMemsetAsync(counts, 0, zeroBytes, stream);

  int gE = (E + 255) / 256;
  cvtidx_k<<<gE, 256, 0, stream>>>(eix, src32, dst32, counts, E);
  scanA_k<<<nb, 256, 0, stream>>>(counts, bsums, M);
  scanC_k<<<nb, 256, 0, stream>>>(counts, bsums, offs, cursor, M, E, nb);
  fill_k<<<gE, 256, 0, stream>>>(src32, dst32, cursor, csr, E);

  int gW = (N1 * (D_IN / 8) + 255) / 256;
  cvtw_k<<<gW, 256, 0, stream>>>(W1l, W1r, wb);

  gemm_k<<<gemmBlocks, 256, 0, stream>>>(x, wb, Cb, M, MT, mtPerXcd);

  agg_l2_k<<<(M + 3) / 4, 256, 0, stream>>>(Cb, offs, csr, b1, W2l, W2r, rs, M);
  final_k<<<(M + 255) / 256, 256, 0, stream>>>(rs, offs, csr, b2, out, M);
}